// Round 1
// baseline (181.572 us; speedup 1.0000x reference)
//
#include <hip/hip_runtime.h>
#include <math.h>

// Problem constants (fixed by the reference)
#define NN   5000
#define BB   4
#define SEQ  128
#define OUTC 128
#define EE   80000
#define KTOT 384   // [X | Txo | Txi]
#define CTOT 256   // [Z-preact | H-preact]

// ---------------------------------------------------------------------------
// Weight prep: fold Wz/Wh into one Wcat[384][256].
//   k<128   : X    rows -> W[0,0]+W[1,0]  (first 128 rows only; H0 part is 0)
//   128-255 : Txo  rows -> W[0,1]
//   256-383 : Txi  rows -> W[1,1]
//   c<128 uses Wz (Z gate), c>=128 uses Wh (candidate). bcat = [bz | bh].
// W layout: [2][2][256][128] -> ((k0*2+k1)*256 + r)*128 + o
// ---------------------------------------------------------------------------
__global__ void k_prep_w(const float* __restrict__ Wz, const float* __restrict__ bz,
                         const float* __restrict__ Wh, const float* __restrict__ bh,
                         float* __restrict__ Wcat, float* __restrict__ bcat) {
    int i = blockIdx.x * blockDim.x + threadIdx.x;
    if (i < CTOT) bcat[i] = (i < OUTC) ? bz[i] : bh[i - OUTC];
    if (i >= KTOT * CTOT) return;
    int k = i / CTOT, c = i % CTOT;
    const float* W = (c < OUTC) ? Wz : Wh;
    int o = c & (OUTC - 1);
    int r = k & 127;
    int p = k >> 7;
    float v;
    if (p == 0)      v = W[(0 * 256 + r) * 128 + o] + W[(2 * 256 + r) * 128 + o];
    else if (p == 1) v = W[(1 * 256 + r) * 128 + o];
    else             v = W[(3 * 256 + r) * 128 + o];
    Wcat[i] = v;
}

// ---------------------------------------------------------------------------
// Degrees + CSR counts
// ---------------------------------------------------------------------------
__global__ void k_deg(const int* __restrict__ ei, const float* __restrict__ ew,
                      float* deg_out, float* deg_in,
                      unsigned* cnt_in, unsigned* cnt_out) {
    int e = blockIdx.x * blockDim.x + threadIdx.x;
    if (e >= EE) return;
    int s = ei[e], d = ei[EE + e];
    float w = ew[e];
    atomicAdd(&deg_out[s], w);
    atomicAdd(&deg_in[d], w);
    atomicAdd(&cnt_out[s], 1u);
    atomicAdd(&cnt_in[d], 1u);
}

// ---------------------------------------------------------------------------
// Single-block exclusive scan of both count arrays (N=5000, 1024 thr x 5 each)
// ---------------------------------------------------------------------------
__global__ void k_scan(const unsigned* __restrict__ cnt_in,
                       const unsigned* __restrict__ cnt_out,
                       unsigned* __restrict__ off_in, unsigned* __restrict__ off_out) {
    __shared__ unsigned sdata[1024];
    int t = threadIdx.x;
    for (int a = 0; a < 2; ++a) {
        const unsigned* cnt = a ? cnt_out : cnt_in;
        unsigned* off = a ? off_out : off_in;
        unsigned loc[5];
        unsigned sum = 0;
        int base = t * 5;
#pragma unroll
        for (int j = 0; j < 5; ++j) {
            int idx = base + j;
            unsigned v = (idx < NN) ? cnt[idx] : 0u;
            loc[j] = sum;
            sum += v;
        }
        sdata[t] = sum;
        __syncthreads();
        for (int o = 1; o < 1024; o <<= 1) {
            unsigned v = (t >= o) ? sdata[t - o] : 0u;
            __syncthreads();
            sdata[t] += v;
            __syncthreads();
        }
        unsigned tb = (t > 0) ? sdata[t - 1] : 0u;
#pragma unroll
        for (int j = 0; j < 5; ++j) {
            int idx = base + j;
            if (idx < NN) off[idx] = tb + loc[j];
        }
        __syncthreads();
    }
}

// ---------------------------------------------------------------------------
// Fill CSR lists: grouped-by-dst (reads src, coef_o) and grouped-by-src
// (reads dst, coef_i).
// ---------------------------------------------------------------------------
__global__ void k_fill(const int* __restrict__ ei, const float* __restrict__ ew,
                       const float* __restrict__ deg_out, const float* __restrict__ deg_in,
                       const unsigned* __restrict__ off_in, const unsigned* __restrict__ off_out,
                       unsigned* cur_in, unsigned* cur_out,
                       int* lin_idx, float* lin_cf, int* lout_idx, float* lout_cf) {
    int e = blockIdx.x * blockDim.x + threadIdx.x;
    if (e >= EE) return;
    int s = ei[e], d = ei[EE + e];
    float w = ew[e];
    float go = deg_out[s], gi = deg_in[d];
    float co = (go > 0.f) ? w / go : 0.f;  // coef_o = w * dinv_out[src]
    float ci = (gi > 0.f) ? w / gi : 0.f;  // coef_i = w * dinv_in[dst]
    unsigned p = atomicAdd(&cur_in[d], 1u);
    unsigned pi = off_in[d] + p;
    lin_idx[pi] = s;
    lin_cf[pi] = co;
    unsigned q = atomicAdd(&cur_out[s], 1u);
    unsigned po = off_out[s] + q;
    lout_idx[po] = d;
    lout_cf[po] = ci;
}

// ---------------------------------------------------------------------------
// Diffusion (gather form): one wave per (node, batch). Each lane owns 2
// feature columns. Tx layout: [b][n][256] = [Txo(128) | Txi(128)].
// ---------------------------------------------------------------------------
__global__ __launch_bounds__(256) void k_diffuse(
        const float* __restrict__ x,
        const unsigned* __restrict__ off_in, const unsigned* __restrict__ cnt_in,
        const unsigned* __restrict__ off_out, const unsigned* __restrict__ cnt_out,
        const int* __restrict__ lin_idx, const float* __restrict__ lin_cf,
        const int* __restrict__ lout_idx, const float* __restrict__ lout_cf,
        float* __restrict__ Tx) {
    int wid = blockIdx.x * 4 + (threadIdx.x >> 6);  // 0 .. 19999
    int l = threadIdx.x & 63;
    int n = wid % NN;
    int b = wid / NN;
    const float* xb = x + (size_t)b * NN * SEQ;

    float2 ao = {0.f, 0.f}, ai = {0.f, 0.f};
    unsigned s0 = off_in[n], c0 = cnt_in[n];
    for (unsigned j = 0; j < c0; ++j) {
        int sn = lin_idx[s0 + j];
        float cf = lin_cf[s0 + j];
        float2 xv = *(const float2*)&xb[(size_t)sn * SEQ + 2 * l];
        ao.x += cf * xv.x;
        ao.y += cf * xv.y;
    }
    unsigned s1 = off_out[n], c1 = cnt_out[n];
    for (unsigned j = 0; j < c1; ++j) {
        int dn = lout_idx[s1 + j];
        float cf = lout_cf[s1 + j];
        float2 xv = *(const float2*)&xb[(size_t)dn * SEQ + 2 * l];
        ai.x += cf * xv.x;
        ai.y += cf * xv.y;
    }
    float* txp = Tx + (size_t)(b * NN + n) * 256;
    *(float2*)&txp[2 * l] = ao;
    *(float2*)&txp[128 + 2 * l] = ai;
}

// ---------------------------------------------------------------------------
// GEMM: Pre[b][n][c] = sum_k In[b][n][k] * Wcat[k][c] + bcat[c]
// In cols 0-127 come from x, 128-383 from Tx. 64x64 tile, Kc=32, 4x4/thread.
// ---------------------------------------------------------------------------
#define TM 64
#define TN 64
#define KC 32

__global__ __launch_bounds__(256) void k_gemm(
        const float* __restrict__ x, const float* __restrict__ Tx,
        const float* __restrict__ Wcat, const float* __restrict__ bcat,
        float* __restrict__ Pre) {
    __shared__ float inS[TM][KC + 4];  // stride 36: 2-way max bank aliasing
    __shared__ float wS[KC][TN];
    int b = blockIdx.z;
    int n0 = blockIdx.x * TM;
    int c0 = blockIdx.y * TN;
    int t = threadIdx.x;
    int tm = t >> 4, tn = t & 15;
    float acc[4][4] = {};
    const float* xb = x + (size_t)b * NN * SEQ;
    const float* txb = Tx + (size_t)b * NN * 256;

    for (int k0 = 0; k0 < KTOT; k0 += KC) {
        const float* src;
        int rs, kl;
        if (k0 < 128) { src = xb; rs = SEQ; kl = k0; }
        else          { src = txb; rs = 256; kl = k0 - 128; }
        // stage input tile [64][32]
#pragma unroll
        for (int q = 0; q < 2; ++q) {
            int lin = t + q * 256;
            int row = lin >> 3, k4 = (lin & 7) * 4;
            int nn = n0 + row;
            float4 v = {0.f, 0.f, 0.f, 0.f};
            if (nn < NN) v = *(const float4*)&src[(size_t)nn * rs + kl + k4];
            *(float4*)&inS[row][k4] = v;
        }
        // stage weight tile [32][64]
#pragma unroll
        for (int q = 0; q < 2; ++q) {
            int lin = t + q * 256;
            int kr = lin >> 4, c4 = (lin & 15) * 4;
            *(float4*)&wS[kr][c4] = *(const float4*)&Wcat[(size_t)(k0 + kr) * CTOT + c0 + c4];
        }
        __syncthreads();
#pragma unroll
        for (int kk4 = 0; kk4 < KC / 4; ++kk4) {
            float4 a[4];
#pragma unroll
            for (int i = 0; i < 4; ++i) a[i] = *(const float4*)&inS[tm * 4 + i][kk4 * 4];
#pragma unroll
            for (int q = 0; q < 4; ++q) {
                float4 bb = *(const float4*)&wS[kk4 * 4 + q][tn * 4];
#pragma unroll
                for (int i = 0; i < 4; ++i) {
                    float av = (q == 0) ? a[i].x : (q == 1) ? a[i].y : (q == 2) ? a[i].z : a[i].w;
                    acc[i][0] += av * bb.x;
                    acc[i][1] += av * bb.y;
                    acc[i][2] += av * bb.z;
                    acc[i][3] += av * bb.w;
                }
            }
        }
        __syncthreads();
    }
    int c = c0 + tn * 4;
    float4 bi = *(const float4*)&bcat[c];
#pragma unroll
    for (int i = 0; i < 4; ++i) {
        int nn = n0 + tm * 4 + i;
        if (nn >= NN) continue;
        float4 o;
        o.x = acc[i][0] + bi.x;
        o.y = acc[i][1] + bi.y;
        o.z = acc[i][2] + bi.z;
        o.w = acc[i][3] + bi.w;
        *(float4*)&Pre[(size_t)(b * NN + nn) * CTOT + c] = o;
    }
}

// ---------------------------------------------------------------------------
// Epilogue: out = (1 - sigmoid(preZ)) * tanh(preH)
// ---------------------------------------------------------------------------
__global__ void k_epi(const float* __restrict__ Pre, float* __restrict__ out) {
    int i = blockIdx.x * blockDim.x + threadIdx.x;
    if (i >= BB * NN * OUTC) return;
    int o = i & 127;
    int bn = i >> 7;
    const float* p = Pre + (size_t)bn * CTOT;
    float z = 1.f / (1.f + expf(-p[o]));
    float h = tanhf(p[OUTC + o]);
    out[i] = (1.f - z) * h;
}

// ---------------------------------------------------------------------------
extern "C" void kernel_launch(void* const* d_in, const int* in_sizes, int n_in,
                              void* d_out, int out_size, void* d_ws, size_t ws_size,
                              hipStream_t stream) {
    const float* x  = (const float*)d_in[0];
    const int*   ei = (const int*)d_in[1];
    const float* ew = (const float*)d_in[2];
    const float* Wz = (const float*)d_in[3];
    const float* bz = (const float*)d_in[4];
    // d_in[5]=Wr, d_in[6]=br are dead code (H0==0 -> Xc2==Xc)
    const float* Wh = (const float*)d_in[7];
    const float* bh = (const float*)d_in[8];

    float* ws = (float*)d_ws;
    float*    deg_out = ws + 0;          // 5000
    float*    deg_in  = ws + 5000;       // 5000
    unsigned* cnt_in  = (unsigned*)(ws + 10000);
    unsigned* cnt_out = (unsigned*)(ws + 15000);
    unsigned* cur_in  = (unsigned*)(ws + 20000);
    unsigned* cur_out = (unsigned*)(ws + 25000);
    unsigned* off_in  = (unsigned*)(ws + 30000);
    unsigned* off_out = (unsigned*)(ws + 35000);
    int*      lin_idx  = (int*)(ws + 40000);    // E
    float*    lin_cf   = ws + 120000;           // E
    int*      lout_idx = (int*)(ws + 200000);   // E
    float*    lout_cf  = ws + 280000;           // E
    float*    Wcat = ws + 360000;               // 384*256
    float*    bcat = ws + 458304;               // 256
    float*    Tx   = ws + 458560;               // 4*5000*256
    float*    Pre  = ws + 5578560;              // 4*5000*256

    // zero deg/cnt/cur (30000 floats)
    hipMemsetAsync(ws, 0, 30000 * sizeof(float), stream);

    k_prep_w<<<(KTOT * CTOT + 255) / 256, 256, 0, stream>>>(Wz, bz, Wh, bh, Wcat, bcat);
    k_deg<<<(EE + 255) / 256, 256, 0, stream>>>(ei, ew, deg_out, deg_in, cnt_in, cnt_out);
    k_scan<<<1, 1024, 0, stream>>>(cnt_in, cnt_out, off_in, off_out);
    k_fill<<<(EE + 255) / 256, 256, 0, stream>>>(ei, ew, deg_out, deg_in, off_in, off_out,
                                                 cur_in, cur_out,
                                                 lin_idx, lin_cf, lout_idx, lout_cf);
    k_diffuse<<<NN, 256, 0, stream>>>(x, off_in, cnt_in, off_out, cnt_out,
                                      lin_idx, lin_cf, lout_idx, lout_cf, Tx);
    dim3 g((NN + TM - 1) / TM, CTOT / TN, BB);
    k_gemm<<<g, 256, 0, stream>>>(x, Tx, Wcat, bcat, Pre);
    k_epi<<<(BB * NN * OUTC + 255) / 256, 256, 0, stream>>>(Pre, (float*)d_out);
}

// Round 2
// 109.353 us; speedup vs baseline: 1.6604x; 1.6604x over previous
//
#include <hip/hip_runtime.h>
#include <math.h>

// Problem constants (fixed by the reference)
#define NN   5000
#define BB   4
#define SEQ  128
#define OUTC 128
#define EE   80000
#define KTOT 384   // [X | Txo | Txi]
#define CTOT 256   // interleaved: col cc = 2*o + gate (gate 0=Z, 1=H)
#define MTOT (BB * NN)   // 20000
#define MPAD 20096       // 157 * 128

typedef __attribute__((ext_vector_type(8))) short bf16x8;
typedef __attribute__((ext_vector_type(4))) float f32x4;

__device__ inline unsigned short f2bf(float f) {   // RNE float->bf16
    union { float f; unsigned u; } a; a.f = f;
    unsigned r = a.u + 0x7FFF + ((a.u >> 16) & 1);
    return (unsigned short)(r >> 16);
}

// ---------------------------------------------------------------------------
// Weight prep: WT[cc][k] bf16, cc = 2*o + gate. k<128: W[0,0]+W[1,0] rows
// (H0 part dead); 128-255: W[0,1]; 256-383: W[1,1]. bcat2[cc] interleaved.
// W layout [2][2][256][128]: ((k0*2+k1)*256 + r)*128 + o
// ---------------------------------------------------------------------------
__global__ void k_prep_w(const float* __restrict__ Wz, const float* __restrict__ bz,
                         const float* __restrict__ Wh, const float* __restrict__ bh,
                         unsigned short* __restrict__ WT, float* __restrict__ bcat2) {
    int i = blockIdx.x * blockDim.x + threadIdx.x;
    if (i < CTOT) bcat2[i] = (i & 1) ? bh[i >> 1] : bz[i >> 1];
    if (i >= CTOT * KTOT) return;
    int cc = i / KTOT, k = i % KTOT;
    int gate = cc & 1, o = cc >> 1;
    const float* W = gate ? Wh : Wz;
    float v;
    if (k < 128)      v = W[(size_t)k * 128 + o] + W[(size_t)(512 + k) * 128 + o];
    else if (k < 256) v = W[(size_t)(256 + (k - 128)) * 128 + o];
    else              v = W[(size_t)(768 + (k - 256)) * 128 + o];
    WT[(size_t)cc * KTOT + k] = f2bf(v);
}

// ---------------------------------------------------------------------------
// Degrees + CSR counts
// ---------------------------------------------------------------------------
__global__ void k_deg(const int* __restrict__ ei, const float* __restrict__ ew,
                      float* deg_out, float* deg_in,
                      unsigned* cnt_in, unsigned* cnt_out) {
    int e = blockIdx.x * blockDim.x + threadIdx.x;
    if (e >= EE) return;
    int s = ei[e], d = ei[EE + e];
    float w = ew[e];
    atomicAdd(&deg_out[s], w);
    atomicAdd(&deg_in[d], w);
    atomicAdd(&cnt_out[s], 1u);
    atomicAdd(&cnt_in[d], 1u);
}

// ---------------------------------------------------------------------------
// Single-block exclusive scan of both count arrays
// ---------------------------------------------------------------------------
__global__ void k_scan(const unsigned* __restrict__ cnt_in,
                       const unsigned* __restrict__ cnt_out,
                       unsigned* __restrict__ off_in, unsigned* __restrict__ off_out) {
    __shared__ unsigned sdata[1024];
    int t = threadIdx.x;
    for (int a = 0; a < 2; ++a) {
        const unsigned* cnt = a ? cnt_out : cnt_in;
        unsigned* off = a ? off_out : off_in;
        unsigned loc[5];
        unsigned sum = 0;
        int base = t * 5;
#pragma unroll
        for (int j = 0; j < 5; ++j) {
            int idx = base + j;
            unsigned v = (idx < NN) ? cnt[idx] : 0u;
            loc[j] = sum;
            sum += v;
        }
        sdata[t] = sum;
        __syncthreads();
        for (int o = 1; o < 1024; o <<= 1) {
            unsigned v = (t >= o) ? sdata[t - o] : 0u;
            __syncthreads();
            sdata[t] += v;
            __syncthreads();
        }
        unsigned tb = (t > 0) ? sdata[t - 1] : 0u;
#pragma unroll
        for (int j = 0; j < 5; ++j) {
            int idx = base + j;
            if (idx < NN) off[idx] = tb + loc[j];
        }
        __syncthreads();
    }
}

// ---------------------------------------------------------------------------
// Fill CSR lists
// ---------------------------------------------------------------------------
__global__ void k_fill(const int* __restrict__ ei, const float* __restrict__ ew,
                       const float* __restrict__ deg_out, const float* __restrict__ deg_in,
                       const unsigned* __restrict__ off_in, const unsigned* __restrict__ off_out,
                       unsigned* cur_in, unsigned* cur_out,
                       int* lin_idx, float* lin_cf, int* lout_idx, float* lout_cf) {
    int e = blockIdx.x * blockDim.x + threadIdx.x;
    if (e >= EE) return;
    int s = ei[e], d = ei[EE + e];
    float w = ew[e];
    float go = deg_out[s], gi = deg_in[d];
    float co = (go > 0.f) ? w / go : 0.f;
    float ci = (gi > 0.f) ? w / gi : 0.f;
    unsigned p = atomicAdd(&cur_in[d], 1u);
    unsigned pi = off_in[d] + p;
    lin_idx[pi] = s;
    lin_cf[pi] = co;
    unsigned q = atomicAdd(&cur_out[s], 1u);
    unsigned po = off_out[s] + q;
    lout_idx[po] = d;
    lout_cf[po] = ci;
}

// ---------------------------------------------------------------------------
// Gather one CSR list with register-staged idx/coef (shuffle broadcast) and
// 4-wide explicit load pipelining. Lane l owns cols 2l, 2l+1.
// ---------------------------------------------------------------------------
__device__ inline float2 gather_list(const float* __restrict__ xb,
                                     const int* __restrict__ idx_l,
                                     const float* __restrict__ cf_l,
                                     unsigned st, unsigned cnt, int l) {
    float2 a = {0.f, 0.f};
    for (unsigned base = 0; base < cnt; base += 64) {
        int m = (int)((cnt - base < 64u) ? (cnt - base) : 64u);
        int id = 0; float cf = 0.f;
        if (l < m) { id = idx_l[st + base + l]; cf = cf_l[st + base + l]; }
        int j = 0;
        for (; j + 3 < m; j += 4) {
            int i0 = __shfl(id, j),     i1 = __shfl(id, j + 1);
            int i2 = __shfl(id, j + 2), i3 = __shfl(id, j + 3);
            float c0 = __shfl(cf, j),     c1 = __shfl(cf, j + 1);
            float c2 = __shfl(cf, j + 2), c3 = __shfl(cf, j + 3);
            float2 v0 = *(const float2*)&xb[(size_t)i0 * SEQ + 2 * l];
            float2 v1 = *(const float2*)&xb[(size_t)i1 * SEQ + 2 * l];
            float2 v2 = *(const float2*)&xb[(size_t)i2 * SEQ + 2 * l];
            float2 v3 = *(const float2*)&xb[(size_t)i3 * SEQ + 2 * l];
            a.x += c0 * v0.x; a.y += c0 * v0.y;
            a.x += c1 * v1.x; a.y += c1 * v1.y;
            a.x += c2 * v2.x; a.y += c2 * v2.y;
            a.x += c3 * v3.x; a.y += c3 * v3.y;
        }
        for (; j < m; ++j) {
            int i0 = __shfl(id, j); float c0 = __shfl(cf, j);
            float2 v0 = *(const float2*)&xb[(size_t)i0 * SEQ + 2 * l];
            a.x += c0 * v0.x; a.y += c0 * v0.y;
        }
    }
    return a;
}

// ---------------------------------------------------------------------------
// Diffusion + bf16 pack of [x | Txo | Txi] into Inb[20000][384].
// XCD-batch swizzle: blockIdx%8 = xcd slot, batch = slot>>1 so each XCD's L2
// only holds one batch's 2.56 MB x slice. 5000 blocks = 625*8, 4 waves/block,
// one wave per node.
// ---------------------------------------------------------------------------
__global__ __launch_bounds__(256) void k_diffuse(
        const float* __restrict__ x,
        const unsigned* __restrict__ off_in, const unsigned* __restrict__ cnt_in,
        const unsigned* __restrict__ off_out, const unsigned* __restrict__ cnt_out,
        const int* __restrict__ lin_idx, const float* __restrict__ lin_cf,
        const int* __restrict__ lout_idx, const float* __restrict__ lout_cf,
        unsigned short* __restrict__ Inb) {
    int bid = blockIdx.x;
    int slot = bid & 7, pos = bid >> 3;
    int b = slot >> 1;
    int n = (pos * 2 + (slot & 1)) * 4 + (threadIdx.x >> 6);
    int l = threadIdx.x & 63;
    const float* xb = x + (size_t)b * NN * SEQ;

    float2 xo = *(const float2*)&xb[(size_t)n * SEQ + 2 * l];  // own row (issued early)
    float2 ao = gather_list(xb, lin_idx, lin_cf, off_in[n], cnt_in[n], l);
    float2 ai = gather_list(xb, lout_idx, lout_cf, off_out[n], cnt_out[n], l);

    unsigned short* r = Inb + (size_t)(b * NN + n) * KTOT;
    *(unsigned*)&r[2 * l]       = (unsigned)f2bf(xo.x) | ((unsigned)f2bf(xo.y) << 16);
    *(unsigned*)&r[128 + 2 * l] = (unsigned)f2bf(ao.x) | ((unsigned)f2bf(ao.y) << 16);
    *(unsigned*)&r[256 + 2 * l] = (unsigned)f2bf(ai.x) | ((unsigned)f2bf(ai.y) << 16);
}

// ---------------------------------------------------------------------------
// MFMA GEMM + fused epilogue.
// D[row][cc] = sum_k Inb[row][k] * WT[cc][k], 16x16x32 bf16 MFMA.
// BM=128, BN=128, 4 waves (2x2 of 64x64). LDS fragment-linear (frag f: 1KB,
// lane l: 16B at f*1024+l*16) so global_load_lds dest is linear and
// ds_read_b128 is conflict-free. Epilogue: cols interleaved (cc=2o+gate) ->
// shfl_xor(1) pairs Z/H, write (1-sigm(z))*tanh(h) to out.
// ---------------------------------------------------------------------------
__global__ __launch_bounds__(256) void k_mm(
        const unsigned short* __restrict__ Inb, const unsigned short* __restrict__ WT,
        const float* __restrict__ bcat2, float* __restrict__ out) {
    __shared__ unsigned short lA[4096];  // 8 frags x 64 lanes x 8 bf16
    __shared__ unsigned short lB[4096];
    int t = threadIdx.x, w = t >> 6, l = t & 63;
    int lr = l & 15, lk = l >> 4;
    int n0 = blockIdx.x * 128;
    int c0 = blockIdx.y * 128;
    int wr = w >> 1, wc = w & 1;
    f32x4 acc[4][4] = {};

    for (int k0 = 0; k0 < KTOT; k0 += 32) {
#pragma unroll
        for (int q = 0; q < 2; ++q) {
            int f = w * 2 + q;  // wave-uniform fragment index
            const unsigned short* sa = Inb + (size_t)(n0 + f * 16 + lr) * KTOT + k0 + lk * 8;
            __builtin_amdgcn_global_load_lds(
                (const __attribute__((address_space(1))) void*)sa,
                (__attribute__((address_space(3))) void*)&lA[f * 512], 16, 0, 0);
            const unsigned short* sb = WT + (size_t)(c0 + f * 16 + lr) * KTOT + k0 + lk * 8;
            __builtin_amdgcn_global_load_lds(
                (const __attribute__((address_space(1))) void*)sb,
                (__attribute__((address_space(3))) void*)&lB[f * 512], 16, 0, 0);
        }
        __syncthreads();
        bf16x8 a[4], bfr[4];
#pragma unroll
        for (int i = 0; i < 4; ++i) a[i] = *(const bf16x8*)&lA[(wr * 4 + i) * 512 + l * 8];
#pragma unroll
        for (int j = 0; j < 4; ++j) bfr[j] = *(const bf16x8*)&lB[(wc * 4 + j) * 512 + l * 8];
#pragma unroll
        for (int i = 0; i < 4; ++i)
#pragma unroll
            for (int j = 0; j < 4; ++j)
                acc[i][j] = __builtin_amdgcn_mfma_f32_16x16x32_bf16(a[i], bfr[j], acc[i][j], 0, 0, 0);
        __syncthreads();
    }

    // Epilogue: C row = n0+wr*64+i*16+lk*4+reg, col cc = c0+wc*64+j*16+lr
    int row_base = n0 + wr * 64;
#pragma unroll
    for (int j = 0; j < 4; ++j) {
        int cc = c0 + wc * 64 + j * 16 + lr;
        float bias = bcat2[cc];
        int o = cc >> 1;
#pragma unroll
        for (int i = 0; i < 4; ++i) {
#pragma unroll
            for (int rr = 0; rr < 4; ++rr) {
                float v = acc[i][j][rr] + bias;
                float p = __shfl_xor(v, 1);
                if (!(l & 1)) {
                    float z = 1.f / (1.f + __expf(-v));
                    float h = tanhf(p);
                    int row = row_base + i * 16 + lk * 4 + rr;
                    if (row < MTOT) out[(size_t)row * OUTC + o] = (1.f - z) * h;
                }
            }
        }
    }
}

// ---------------------------------------------------------------------------
extern "C" void kernel_launch(void* const* d_in, const int* in_sizes, int n_in,
                              void* d_out, int out_size, void* d_ws, size_t ws_size,
                              hipStream_t stream) {
    const float* x  = (const float*)d_in[0];
    const int*   ei = (const int*)d_in[1];
    const float* ew = (const float*)d_in[2];
    const float* Wz = (const float*)d_in[3];
    const float* bz = (const float*)d_in[4];
    // d_in[5]=Wr, d_in[6]=br dead (H0==0 -> Xc2==Xc, R unused)
    const float* Wh = (const float*)d_in[7];
    const float* bh = (const float*)d_in[8];

    float* ws = (float*)d_ws;
    float*    deg_out = ws + 0;
    float*    deg_in  = ws + 5000;
    unsigned* cnt_in  = (unsigned*)(ws + 10000);
    unsigned* cnt_out = (unsigned*)(ws + 15000);
    unsigned* cur_in  = (unsigned*)(ws + 20000);
    unsigned* cur_out = (unsigned*)(ws + 25000);
    unsigned* off_in  = (unsigned*)(ws + 30000);
    unsigned* off_out = (unsigned*)(ws + 35000);
    int*      lin_idx  = (int*)(ws + 40000);     // E
    float*    lin_cf   = ws + 120000;            // E
    int*      lout_idx = (int*)(ws + 200000);    // E
    float*    lout_cf  = ws + 280000;            // E
    float*    bcat2    = ws + 360000;            // 256
    unsigned short* WT  = (unsigned short*)(ws + 360256);   // 256*384 bf16
    unsigned short* Inb = (unsigned short*)(ws + 409408);   // MPAD*384 bf16

    hipMemsetAsync(ws, 0, 30000 * sizeof(float), stream);  // deg/cnt/cur

    k_prep_w<<<(CTOT * KTOT + 255) / 256, 256, 0, stream>>>(Wz, bz, Wh, bh, WT, bcat2);
    k_deg<<<(EE + 255) / 256, 256, 0, stream>>>(ei, ew, deg_out, deg_in, cnt_in, cnt_out);
    k_scan<<<1, 1024, 0, stream>>>(cnt_in, cnt_out, off_in, off_out);
    k_fill<<<(EE + 255) / 256, 256, 0, stream>>>(ei, ew, deg_out, deg_in, off_in, off_out,
                                                 cur_in, cur_out,
                                                 lin_idx, lin_cf, lout_idx, lout_cf);
    k_diffuse<<<NN, 256, 0, stream>>>(x, off_in, cnt_in, off_out, cnt_out,
                                      lin_idx, lin_cf, lout_idx, lout_cf, Inb);
    dim3 g(MPAD / 128, 2);
    k_mm<<<g, 256, 0, stream>>>(Inb, WT, bcat2, (float*)d_out);
}

// Round 3
// 106.533 us; speedup vs baseline: 1.7044x; 1.0265x over previous
//
#include <hip/hip_runtime.h>
#include <math.h>

// Problem constants (fixed by the reference)
#define NN   5000
#define BB   4
#define SEQ  128
#define OUTC 128
#define EE   80000
#define KTOT 384   // [X | Txo | Txi]
#define CTOT 256   // interleaved: col cc = 2*o + gate (gate 0=Z, 1=H)
#define MTOT (BB * NN)   // 20000
#define MPAD 20096       // 157 * 128

typedef __attribute__((ext_vector_type(8))) short bf16x8;
typedef __attribute__((ext_vector_type(4))) float f32x4;

__device__ inline unsigned short f2bf(float f) {   // RNE float->bf16
    union { float f; unsigned u; } a; a.f = f;
    unsigned r = a.u + 0x7FFF + ((a.u >> 16) & 1);
    return (unsigned short)(r >> 16);
}

// ---------------------------------------------------------------------------
// Fused init: (a) zero deg/cnt/cur region (30000 floats, float4 stores —
// replaces hipMemsetAsync whose fillBufferAligned kernel cost ~44us/replay),
// (b) fold weights into WT[cc][k] bf16 (cc = 2*o + gate), (c) bias interleave.
// W layout [2][2][256][128]: ((k0*2+k1)*256 + r)*128 + o. H0 rows dead.
// ---------------------------------------------------------------------------
__global__ __launch_bounds__(256) void k_init(
        const float* __restrict__ Wz, const float* __restrict__ bz,
        const float* __restrict__ Wh, const float* __restrict__ bh,
        unsigned short* __restrict__ WT, float* __restrict__ bcat2,
        float* __restrict__ zero_region) {
    int i = blockIdx.x * blockDim.x + threadIdx.x;
    if (i < 7500) {
        f32x4 z = {0.f, 0.f, 0.f, 0.f};
        *(f32x4*)&zero_region[i * 4] = z;
    }
    if (i < CTOT) bcat2[i] = (i & 1) ? bh[i >> 1] : bz[i >> 1];
    if (i >= CTOT * KTOT) return;
    int cc = i / KTOT, k = i % KTOT;
    int gate = cc & 1, o = cc >> 1;
    const float* W = gate ? Wh : Wz;
    float v;
    if (k < 128)      v = W[(size_t)k * 128 + o] + W[(size_t)(512 + k) * 128 + o];
    else if (k < 256) v = W[(size_t)(256 + (k - 128)) * 128 + o];
    else              v = W[(size_t)(768 + (k - 256)) * 128 + o];
    WT[(size_t)cc * KTOT + k] = f2bf(v);
}

// ---------------------------------------------------------------------------
// Degrees + CSR counts
// ---------------------------------------------------------------------------
__global__ void k_deg(const int* __restrict__ ei, const float* __restrict__ ew,
                      float* deg_out, float* deg_in,
                      unsigned* cnt_in, unsigned* cnt_out) {
    int e = blockIdx.x * blockDim.x + threadIdx.x;
    if (e >= EE) return;
    int s = ei[e], d = ei[EE + e];
    float w = ew[e];
    atomicAdd(&deg_out[s], w);
    atomicAdd(&deg_in[d], w);
    atomicAdd(&cnt_out[s], 1u);
    atomicAdd(&cnt_in[d], 1u);
}

// ---------------------------------------------------------------------------
// Single-block exclusive scan of both count arrays
// ---------------------------------------------------------------------------
__global__ void k_scan(const unsigned* __restrict__ cnt_in,
                       const unsigned* __restrict__ cnt_out,
                       unsigned* __restrict__ off_in, unsigned* __restrict__ off_out) {
    __shared__ unsigned sdata[1024];
    int t = threadIdx.x;
    for (int a = 0; a < 2; ++a) {
        const unsigned* cnt = a ? cnt_out : cnt_in;
        unsigned* off = a ? off_out : off_in;
        unsigned loc[5];
        unsigned sum = 0;
        int base = t * 5;
#pragma unroll
        for (int j = 0; j < 5; ++j) {
            int idx = base + j;
            unsigned v = (idx < NN) ? cnt[idx] : 0u;
            loc[j] = sum;
            sum += v;
        }
        sdata[t] = sum;
        __syncthreads();
        for (int o = 1; o < 1024; o <<= 1) {
            unsigned v = (t >= o) ? sdata[t - o] : 0u;
            __syncthreads();
            sdata[t] += v;
            __syncthreads();
        }
        unsigned tb = (t > 0) ? sdata[t - 1] : 0u;
#pragma unroll
        for (int j = 0; j < 5; ++j) {
            int idx = base + j;
            if (idx < NN) off[idx] = tb + loc[j];
        }
        __syncthreads();
    }
}

// ---------------------------------------------------------------------------
// Fill CSR lists
// ---------------------------------------------------------------------------
__global__ void k_fill(const int* __restrict__ ei, const float* __restrict__ ew,
                       const float* __restrict__ deg_out, const float* __restrict__ deg_in,
                       const unsigned* __restrict__ off_in, const unsigned* __restrict__ off_out,
                       unsigned* cur_in, unsigned* cur_out,
                       int* lin_idx, float* lin_cf, int* lout_idx, float* lout_cf) {
    int e = blockIdx.x * blockDim.x + threadIdx.x;
    if (e >= EE) return;
    int s = ei[e], d = ei[EE + e];
    float w = ew[e];
    float go = deg_out[s], gi = deg_in[d];
    float co = (go > 0.f) ? w / go : 0.f;
    float ci = (gi > 0.f) ? w / gi : 0.f;
    unsigned p = atomicAdd(&cur_in[d], 1u);
    unsigned pi = off_in[d] + p;
    lin_idx[pi] = s;
    lin_cf[pi] = co;
    unsigned q = atomicAdd(&cur_out[s], 1u);
    unsigned po = off_out[s] + q;
    lout_idx[po] = d;
    lout_cf[po] = ci;
}

// ---------------------------------------------------------------------------
// Gather one CSR list with register-staged idx/coef (shuffle broadcast) and
// 4-wide explicit load pipelining. Lane l owns cols 2l, 2l+1.
// ---------------------------------------------------------------------------
__device__ inline float2 gather_list(const float* __restrict__ xb,
                                     const int* __restrict__ idx_l,
                                     const float* __restrict__ cf_l,
                                     unsigned st, unsigned cnt, int l) {
    float2 a = {0.f, 0.f};
    for (unsigned base = 0; base < cnt; base += 64) {
        int m = (int)((cnt - base < 64u) ? (cnt - base) : 64u);
        int id = 0; float cf = 0.f;
        if (l < m) { id = idx_l[st + base + l]; cf = cf_l[st + base + l]; }
        int j = 0;
        for (; j + 3 < m; j += 4) {
            int i0 = __shfl(id, j),     i1 = __shfl(id, j + 1);
            int i2 = __shfl(id, j + 2), i3 = __shfl(id, j + 3);
            float c0 = __shfl(cf, j),     c1 = __shfl(cf, j + 1);
            float c2 = __shfl(cf, j + 2), c3 = __shfl(cf, j + 3);
            float2 v0 = *(const float2*)&xb[(size_t)i0 * SEQ + 2 * l];
            float2 v1 = *(const float2*)&xb[(size_t)i1 * SEQ + 2 * l];
            float2 v2 = *(const float2*)&xb[(size_t)i2 * SEQ + 2 * l];
            float2 v3 = *(const float2*)&xb[(size_t)i3 * SEQ + 2 * l];
            a.x += c0 * v0.x; a.y += c0 * v0.y;
            a.x += c1 * v1.x; a.y += c1 * v1.y;
            a.x += c2 * v2.x; a.y += c2 * v2.y;
            a.x += c3 * v3.x; a.y += c3 * v3.y;
        }
        for (; j < m; ++j) {
            int i0 = __shfl(id, j); float c0 = __shfl(cf, j);
            float2 v0 = *(const float2*)&xb[(size_t)i0 * SEQ + 2 * l];
            a.x += c0 * v0.x; a.y += c0 * v0.y;
        }
    }
    return a;
}

// ---------------------------------------------------------------------------
// Diffusion + bf16 pack of [x | Txo | Txi] into Inb[20000][384].
// XCD-batch swizzle: blockIdx%8 = xcd slot, batch = slot>>1 so each XCD's L2
// only holds one batch's 2.56 MB x slice. 5000 blocks, 4 waves/block,
// one wave per node.
// ---------------------------------------------------------------------------
__global__ __launch_bounds__(256) void k_diffuse(
        const float* __restrict__ x,
        const unsigned* __restrict__ off_in, const unsigned* __restrict__ cnt_in,
        const unsigned* __restrict__ off_out, const unsigned* __restrict__ cnt_out,
        const int* __restrict__ lin_idx, const float* __restrict__ lin_cf,
        const int* __restrict__ lout_idx, const float* __restrict__ lout_cf,
        unsigned short* __restrict__ Inb) {
    int bid = blockIdx.x;
    int slot = bid & 7, pos = bid >> 3;
    int b = slot >> 1;
    int n = (pos * 2 + (slot & 1)) * 4 + (threadIdx.x >> 6);
    int l = threadIdx.x & 63;
    const float* xb = x + (size_t)b * NN * SEQ;

    float2 xo = *(const float2*)&xb[(size_t)n * SEQ + 2 * l];  // own row (issued early)
    float2 ao = gather_list(xb, lin_idx, lin_cf, off_in[n], cnt_in[n], l);
    float2 ai = gather_list(xb, lout_idx, lout_cf, off_out[n], cnt_out[n], l);

    unsigned short* r = Inb + (size_t)(b * NN + n) * KTOT;
    *(unsigned*)&r[2 * l]       = (unsigned)f2bf(xo.x) | ((unsigned)f2bf(xo.y) << 16);
    *(unsigned*)&r[128 + 2 * l] = (unsigned)f2bf(ao.x) | ((unsigned)f2bf(ao.y) << 16);
    *(unsigned*)&r[256 + 2 * l] = (unsigned)f2bf(ai.x) | ((unsigned)f2bf(ai.y) << 16);
}

// ---------------------------------------------------------------------------
// MFMA GEMM + fused epilogue.
// D[row][cc] = sum_k Inb[row][k] * WT[cc][k], 16x16x32 bf16 MFMA.
// BM=128, BN=128, 4 waves (2x2 of 64x64). LDS fragment-linear (frag f: 1KB,
// lane l: 16B at f*1024+l*16) so global_load_lds dest is linear and
// ds_read_b128 is conflict-free. Epilogue: cols interleaved (cc=2o+gate) ->
// shfl_xor(1) pairs Z/H, write (1-sigm(z))*tanh(h) to out.
// ---------------------------------------------------------------------------
__global__ __launch_bounds__(256) void k_mm(
        const unsigned short* __restrict__ Inb, const unsigned short* __restrict__ WT,
        const float* __restrict__ bcat2, float* __restrict__ out) {
    __shared__ unsigned short lA[4096];  // 8 frags x 64 lanes x 8 bf16
    __shared__ unsigned short lB[4096];
    int t = threadIdx.x, w = t >> 6, l = t & 63;
    int lr = l & 15, lk = l >> 4;
    int n0 = blockIdx.x * 128;
    int c0 = blockIdx.y * 128;
    int wr = w >> 1, wc = w & 1;
    f32x4 acc[4][4] = {};

    for (int k0 = 0; k0 < KTOT; k0 += 32) {
#pragma unroll
        for (int q = 0; q < 2; ++q) {
            int f = w * 2 + q;  // wave-uniform fragment index
            const unsigned short* sa = Inb + (size_t)(n0 + f * 16 + lr) * KTOT + k0 + lk * 8;
            __builtin_amdgcn_global_load_lds(
                (const __attribute__((address_space(1))) void*)sa,
                (__attribute__((address_space(3))) void*)&lA[f * 512], 16, 0, 0);
            const unsigned short* sb = WT + (size_t)(c0 + f * 16 + lr) * KTOT + k0 + lk * 8;
            __builtin_amdgcn_global_load_lds(
                (const __attribute__((address_space(1))) void*)sb,
                (__attribute__((address_space(3))) void*)&lB[f * 512], 16, 0, 0);
        }
        __syncthreads();
        bf16x8 a[4], bfr[4];
#pragma unroll
        for (int i = 0; i < 4; ++i) a[i] = *(const bf16x8*)&lA[(wr * 4 + i) * 512 + l * 8];
#pragma unroll
        for (int j = 0; j < 4; ++j) bfr[j] = *(const bf16x8*)&lB[(wc * 4 + j) * 512 + l * 8];
#pragma unroll
        for (int i = 0; i < 4; ++i)
#pragma unroll
            for (int j = 0; j < 4; ++j)
                acc[i][j] = __builtin_amdgcn_mfma_f32_16x16x32_bf16(a[i], bfr[j], acc[i][j], 0, 0, 0);
        __syncthreads();
    }

    // Epilogue: C row = n0+wr*64+i*16+lk*4+reg, col cc = c0+wc*64+j*16+lr
    int row_base = n0 + wr * 64;
#pragma unroll
    for (int j = 0; j < 4; ++j) {
        int cc = c0 + wc * 64 + j * 16 + lr;
        float bias = bcat2[cc];
        int o = cc >> 1;
#pragma unroll
        for (int i = 0; i < 4; ++i) {
#pragma unroll
            for (int rr = 0; rr < 4; ++rr) {
                float v = acc[i][j][rr] + bias;
                float p = __shfl_xor(v, 1);
                if (!(l & 1)) {
                    float z = 1.f / (1.f + __expf(-v));
                    float h = tanhf(p);
                    int row = row_base + i * 16 + lk * 4 + rr;
                    if (row < MTOT) out[(size_t)row * OUTC + o] = (1.f - z) * h;
                }
            }
        }
    }
}

// ---------------------------------------------------------------------------
extern "C" void kernel_launch(void* const* d_in, const int* in_sizes, int n_in,
                              void* d_out, int out_size, void* d_ws, size_t ws_size,
                              hipStream_t stream) {
    const float* x  = (const float*)d_in[0];
    const int*   ei = (const int*)d_in[1];
    const float* ew = (const float*)d_in[2];
    const float* Wz = (const float*)d_in[3];
    const float* bz = (const float*)d_in[4];
    // d_in[5]=Wr, d_in[6]=br dead (H0==0 -> Xc2==Xc, R unused)
    const float* Wh = (const float*)d_in[7];
    const float* bh = (const float*)d_in[8];

    float* ws = (float*)d_ws;
    float*    deg_out = ws + 0;
    float*    deg_in  = ws + 5000;
    unsigned* cnt_in  = (unsigned*)(ws + 10000);
    unsigned* cnt_out = (unsigned*)(ws + 15000);
    unsigned* cur_in  = (unsigned*)(ws + 20000);
    unsigned* cur_out = (unsigned*)(ws + 25000);
    unsigned* off_in  = (unsigned*)(ws + 30000);
    unsigned* off_out = (unsigned*)(ws + 35000);
    int*      lin_idx  = (int*)(ws + 40000);     // E
    float*    lin_cf   = ws + 120000;            // E
    int*      lout_idx = (int*)(ws + 200000);    // E
    float*    lout_cf  = ws + 280000;            // E
    float*    bcat2    = ws + 360000;            // 256
    unsigned short* WT  = (unsigned short*)(ws + 360256);   // 256*384 bf16
    unsigned short* Inb = (unsigned short*)(ws + 409408);   // MPAD*384 bf16

    // k_init covers: zero ws[0..30000) + weight fold + bias (replaces memset)
    k_init<<<(CTOT * KTOT + 255) / 256, 256, 0, stream>>>(Wz, bz, Wh, bh, WT, bcat2, ws);
    k_deg<<<(EE + 255) / 256, 256, 0, stream>>>(ei, ew, deg_out, deg_in, cnt_in, cnt_out);
    k_scan<<<1, 1024, 0, stream>>>(cnt_in, cnt_out, off_in, off_out);
    k_fill<<<(EE + 255) / 256, 256, 0, stream>>>(ei, ew, deg_out, deg_in, off_in, off_out,
                                                 cur_in, cur_out,
                                                 lin_idx, lin_cf, lout_idx, lout_cf);
    k_diffuse<<<NN, 256, 0, stream>>>(x, off_in, cnt_in, off_out, cnt_out,
                                      lin_idx, lin_cf, lout_idx, lout_cf, Inb);
    dim3 g(MPAD / 128, 2);
    k_mm<<<g, 256, 0, stream>>>(Inb, WT, bcat2, (float*)d_out);
}

// Round 4
// 87.029 us; speedup vs baseline: 2.0864x; 1.2241x over previous
//
#include <hip/hip_runtime.h>
#include <math.h>

// Problem constants (fixed by the reference)
#define NN   5000
#define BB   4
#define SEQ  128
#define OUTC 128
#define EE   80000
#define KTOT 384   // [X | Txo | Txi]
#define CTOT 256   // interleaved: col cc = 2*o + gate (gate 0=Z, 1=H)
#define MTOT (BB * NN)   // 20000
#define MPAD 20096       // 157 * 128
#define CAP  64          // bucket capacity; Binom(80000,1/5000) max ~40 << 64

typedef __attribute__((ext_vector_type(8))) short bf16x8;
typedef __attribute__((ext_vector_type(4))) float f32x4;

__device__ inline unsigned short f2bf(float f) {   // RNE float->bf16
    union { float f; unsigned u; } a; a.f = f;
    unsigned r = a.u + 0x7FFF + ((a.u >> 16) & 1);
    return (unsigned short)(r >> 16);
}

// ---------------------------------------------------------------------------
// Fused init: zero deg/cnt (20000 floats), fold weights into WT[cc][k] bf16
// (cc = 2*o+gate), interleave bias. W[2][2][256][128]: ((k0*2+k1)*256+r)*128+o
// ---------------------------------------------------------------------------
__global__ __launch_bounds__(256) void k_init(
        const float* __restrict__ Wz, const float* __restrict__ bz,
        const float* __restrict__ Wh, const float* __restrict__ bh,
        unsigned short* __restrict__ WT, float* __restrict__ bcat2,
        float* __restrict__ zero_region) {
    int i = blockIdx.x * blockDim.x + threadIdx.x;
    if (i < 5000) {
        f32x4 z = {0.f, 0.f, 0.f, 0.f};
        *(f32x4*)&zero_region[i * 4] = z;
    }
    if (i < CTOT) bcat2[i] = (i & 1) ? bh[i >> 1] : bz[i >> 1];
    if (i >= CTOT * KTOT) return;
    int cc = i / KTOT, k = i % KTOT;
    int gate = cc & 1, o = cc >> 1;
    const float* W = gate ? Wh : Wz;
    float v;
    if (k < 128)      v = W[(size_t)k * 128 + o] + W[(size_t)(512 + k) * 128 + o];
    else if (k < 256) v = W[(size_t)(256 + (k - 128)) * 128 + o];
    else              v = W[(size_t)(768 + (k - 256)) * 128 + o];
    WT[(size_t)cc * KTOT + k] = f2bf(v);
}

// ---------------------------------------------------------------------------
// One edge pass: weighted degrees (atomic) + fixed-stride buckets (atomic
// slot claim + int2 store). bin[d] holds (src,w) of in-edges of d; bout[s]
// holds (dst,w) of out-edges of s. Replaces deg+scan+fill (3 kernels -> 1).
// ---------------------------------------------------------------------------
__global__ void k_bucket(const int* __restrict__ ei, const float* __restrict__ ew,
                         float* deg_out, float* deg_in,
                         unsigned* cnt_in, unsigned* cnt_out,
                         int2* __restrict__ bin, int2* __restrict__ bout) {
    int e = blockIdx.x * blockDim.x + threadIdx.x;
    if (e >= EE) return;
    int s = ei[e], d = ei[EE + e];
    float w = ew[e];
    atomicAdd(&deg_out[s], w);
    atomicAdd(&deg_in[d], w);
    unsigned p = atomicAdd(&cnt_in[d], 1u);
    if (p < CAP) bin[((size_t)d << 6) + p] = make_int2(s, __float_as_int(w));
    unsigned q = atomicAdd(&cnt_out[s], 1u);
    if (q < CAP) bout[((size_t)s << 6) + q] = make_int2(d, __float_as_int(w));
}

// ---------------------------------------------------------------------------
// Diffusion + bf16 pack of [x | Txo | Txi] into Inb[20000][384].
// One wave per (node,batch). Stage (idx, cf=w/deg[idx]) into wave-private LDS
// (in-order LDS pipe within a wave -> no barrier), then broadcast-read and
// gather rows with 4-wide unroll. XCD-batch swizzle keeps each XCD's L2 on
// one batch's 2.56 MB x slice.
// ---------------------------------------------------------------------------
__global__ __launch_bounds__(256) void k_diffuse(
        const float* __restrict__ x,
        const float* __restrict__ deg_out, const float* __restrict__ deg_in,
        const unsigned* __restrict__ cnt_in, const unsigned* __restrict__ cnt_out,
        const int2* __restrict__ bin, const int2* __restrict__ bout,
        unsigned short* __restrict__ Inb) {
    __shared__ int2 sbA[4][CAP], sbB[4][CAP];
    int bid = blockIdx.x;
    int slot = bid & 7, pos = bid >> 3;
    int b = slot >> 1;
    int wv = threadIdx.x >> 6;
    int n = (pos * 2 + (slot & 1)) * 4 + wv;
    int l = threadIdx.x & 63;
    const float* xb = x + (size_t)b * NN * SEQ;

    float2 xo = *(const float2*)&xb[(size_t)n * SEQ + 2 * l];  // own row, issued early

    int mi = (int)min(cnt_in[n], (unsigned)CAP);
    int mo = (int)min(cnt_out[n], (unsigned)CAP);
    if (l < mi) {   // stage in-list: coef_o = w * dinv_out[src]
        int2 e = bin[((size_t)n << 6) + l];
        float dg = deg_out[e.x];
        float cf = dg > 0.f ? __int_as_float(e.y) / dg : 0.f;
        sbA[wv][l] = make_int2(e.x, __float_as_int(cf));
    }
    if (l < mo) {   // stage out-list: coef_i = w * dinv_in[dst]
        int2 e = bout[((size_t)n << 6) + l];
        float dg = deg_in[e.x];
        float cf = dg > 0.f ? __int_as_float(e.y) / dg : 0.f;
        sbB[wv][l] = make_int2(e.x, __float_as_int(cf));
    }

    float2 ao = {0.f, 0.f}, ai = {0.f, 0.f};
    int j = 0;
    for (; j + 3 < mi; j += 4) {
        int2 e0 = sbA[wv][j], e1 = sbA[wv][j + 1], e2 = sbA[wv][j + 2], e3 = sbA[wv][j + 3];
        float2 v0 = *(const float2*)&xb[(size_t)e0.x * SEQ + 2 * l];
        float2 v1 = *(const float2*)&xb[(size_t)e1.x * SEQ + 2 * l];
        float2 v2 = *(const float2*)&xb[(size_t)e2.x * SEQ + 2 * l];
        float2 v3 = *(const float2*)&xb[(size_t)e3.x * SEQ + 2 * l];
        ao.x += __int_as_float(e0.y) * v0.x; ao.y += __int_as_float(e0.y) * v0.y;
        ao.x += __int_as_float(e1.y) * v1.x; ao.y += __int_as_float(e1.y) * v1.y;
        ao.x += __int_as_float(e2.y) * v2.x; ao.y += __int_as_float(e2.y) * v2.y;
        ao.x += __int_as_float(e3.y) * v3.x; ao.y += __int_as_float(e3.y) * v3.y;
    }
    for (; j < mi; ++j) {
        int2 e0 = sbA[wv][j];
        float2 v0 = *(const float2*)&xb[(size_t)e0.x * SEQ + 2 * l];
        ao.x += __int_as_float(e0.y) * v0.x; ao.y += __int_as_float(e0.y) * v0.y;
    }
    j = 0;
    for (; j + 3 < mo; j += 4) {
        int2 e0 = sbB[wv][j], e1 = sbB[wv][j + 1], e2 = sbB[wv][j + 2], e3 = sbB[wv][j + 3];
        float2 v0 = *(const float2*)&xb[(size_t)e0.x * SEQ + 2 * l];
        float2 v1 = *(const float2*)&xb[(size_t)e1.x * SEQ + 2 * l];
        float2 v2 = *(const float2*)&xb[(size_t)e2.x * SEQ + 2 * l];
        float2 v3 = *(const float2*)&xb[(size_t)e3.x * SEQ + 2 * l];
        ai.x += __int_as_float(e0.y) * v0.x; ai.y += __int_as_float(e0.y) * v0.y;
        ai.x += __int_as_float(e1.y) * v1.x; ai.y += __int_as_float(e1.y) * v1.y;
        ai.x += __int_as_float(e2.y) * v2.x; ai.y += __int_as_float(e2.y) * v2.y;
        ai.x += __int_as_float(e3.y) * v3.x; ai.y += __int_as_float(e3.y) * v3.y;
    }
    for (; j < mo; ++j) {
        int2 e0 = sbB[wv][j];
        float2 v0 = *(const float2*)&xb[(size_t)e0.x * SEQ + 2 * l];
        ai.x += __int_as_float(e0.y) * v0.x; ai.y += __int_as_float(e0.y) * v0.y;
    }

    unsigned short* r = Inb + (size_t)(b * NN + n) * KTOT;
    *(unsigned*)&r[2 * l]       = (unsigned)f2bf(xo.x) | ((unsigned)f2bf(xo.y) << 16);
    *(unsigned*)&r[128 + 2 * l] = (unsigned)f2bf(ao.x) | ((unsigned)f2bf(ao.y) << 16);
    *(unsigned*)&r[256 + 2 * l] = (unsigned)f2bf(ai.x) | ((unsigned)f2bf(ai.y) << 16);
}

// ---------------------------------------------------------------------------
// MFMA GEMM + fused epilogue, 2-phase pipelined (T3-minimum): STAGE(next)
// issued before compute(current); one vmcnt(0)+barrier per K-step so next
// tile's global_load_lds flight hides under the 64 MFMAs.
// D[row][cc] = sum_k Inb[row][k]*WT[cc][k]; cc=2o+gate -> shfl_xor(1) pairs
// Z/H; out = (1-sigmoid(z))*tanh(h).
// ---------------------------------------------------------------------------
__global__ __launch_bounds__(256) void k_mm(
        const unsigned short* __restrict__ Inb, const unsigned short* __restrict__ WT,
        const float* __restrict__ bcat2, float* __restrict__ out) {
    __shared__ unsigned short lA[2][4096];  // [buf][frag f*512 + lane*8]
    __shared__ unsigned short lB[2][4096];
    int t = threadIdx.x, w = t >> 6, l = t & 63;
    int lr = l & 15, lk = l >> 4;
    int n0 = blockIdx.x * 128;
    int c0 = blockIdx.y * 128;
    int wr = w >> 1, wc = w & 1;
    f32x4 acc[4][4] = {};

#define STAGE(buf, k0)                                                            \
    {                                                                             \
        _Pragma("unroll")                                                         \
        for (int q = 0; q < 2; ++q) {                                             \
            int f = w * 2 + q;                                                    \
            const unsigned short* sa = Inb + (size_t)(n0 + f * 16 + lr) * KTOT + (k0) + lk * 8; \
            __builtin_amdgcn_global_load_lds(                                     \
                (const __attribute__((address_space(1))) void*)sa,                \
                (__attribute__((address_space(3))) void*)&lA[buf][f * 512], 16, 0, 0); \
            const unsigned short* sb = WT + (size_t)(c0 + f * 16 + lr) * KTOT + (k0) + lk * 8; \
            __builtin_amdgcn_global_load_lds(                                     \
                (const __attribute__((address_space(1))) void*)sb,                \
                (__attribute__((address_space(3))) void*)&lB[buf][f * 512], 16, 0, 0); \
        }                                                                         \
    }

    STAGE(0, 0);
    asm volatile("s_waitcnt vmcnt(0)" ::: "memory");
    __builtin_amdgcn_s_barrier();

    int cur = 0;
#pragma unroll
    for (int ks = 0; ks < 12; ++ks) {
        if (ks < 11) STAGE(cur ^ 1, (ks + 1) * 32);
        bf16x8 a[4], bfr[4];
#pragma unroll
        for (int i = 0; i < 4; ++i) a[i] = *(const bf16x8*)&lA[cur][(wr * 4 + i) * 512 + l * 8];
#pragma unroll
        for (int jj = 0; jj < 4; ++jj) bfr[jj] = *(const bf16x8*)&lB[cur][(wc * 4 + jj) * 512 + l * 8];
#pragma unroll
        for (int i = 0; i < 4; ++i)
#pragma unroll
            for (int jj = 0; jj < 4; ++jj)
                acc[i][jj] = __builtin_amdgcn_mfma_f32_16x16x32_bf16(a[i], bfr[jj], acc[i][jj], 0, 0, 0);
        asm volatile("s_waitcnt vmcnt(0)" ::: "memory");
        __builtin_amdgcn_s_barrier();
        cur ^= 1;
    }
#undef STAGE

    // Epilogue: row = n0+wr*64+i*16+lk*4+rr, col cc = c0+wc*64+j*16+lr
    int row_base = n0 + wr * 64;
#pragma unroll
    for (int jj = 0; jj < 4; ++jj) {
        int cc = c0 + wc * 64 + jj * 16 + lr;
        float bias = bcat2[cc];
        int o = cc >> 1;
#pragma unroll
        for (int i = 0; i < 4; ++i) {
#pragma unroll
            for (int rr = 0; rr < 4; ++rr) {
                float v = acc[i][jj][rr] + bias;
                float p = __shfl_xor(v, 1);
                if (!(l & 1)) {
                    float z = 1.f / (1.f + __expf(-v));
                    float h = tanhf(p);
                    int row = row_base + i * 16 + lk * 4 + rr;
                    if (row < MTOT) out[(size_t)row * OUTC + o] = (1.f - z) * h;
                }
            }
        }
    }
}

// ---------------------------------------------------------------------------
extern "C" void kernel_launch(void* const* d_in, const int* in_sizes, int n_in,
                              void* d_out, int out_size, void* d_ws, size_t ws_size,
                              hipStream_t stream) {
    const float* x  = (const float*)d_in[0];
    const int*   ei = (const int*)d_in[1];
    const float* ew = (const float*)d_in[2];
    const float* Wz = (const float*)d_in[3];
    const float* bz = (const float*)d_in[4];
    // d_in[5]=Wr, d_in[6]=br dead (H0==0 -> Xc2==Xc, R unused)
    const float* Wh = (const float*)d_in[7];
    const float* bh = (const float*)d_in[8];

    float* ws = (float*)d_ws;
    float*    deg_out = ws + 0;                        // 5000
    float*    deg_in  = ws + 5000;                     // 5000
    unsigned* cnt_in  = (unsigned*)(ws + 10000);       // 5000
    unsigned* cnt_out = (unsigned*)(ws + 15000);       // 5000
    float*    bcat2   = ws + 20000;                    // 256
    unsigned short* WT = (unsigned short*)(ws + 20256);  // 256*384 bf16 (49152 fl)
    int2*     bin  = (int2*)(ws + 69408);              // 5000*64 int2 (640000 fl)
    int2*     bout = (int2*)(ws + 709408);             // 5000*64 int2 (640000 fl)
    unsigned short* Inb = (unsigned short*)(ws + 1349408);  // MPAD*384 bf16

    k_init<<<(CTOT * KTOT + 255) / 256, 256, 0, stream>>>(Wz, bz, Wh, bh, WT, bcat2, ws);
    k_bucket<<<(EE + 255) / 256, 256, 0, stream>>>(ei, ew, deg_out, deg_in,
                                                   cnt_in, cnt_out, bin, bout);
    k_diffuse<<<NN, 256, 0, stream>>>(x, deg_out, deg_in, cnt_in, cnt_out, bin, bout, Inb);
    dim3 g(MPAD / 128, 2);
    k_mm<<<g, 256, 0, stream>>>(Inb, WT, bcat2, (float*)d_out);
}

// Round 5
// 81.416 us; speedup vs baseline: 2.2302x; 1.0689x over previous
//
#include <hip/hip_runtime.h>
#include <math.h>

// Problem constants (fixed by the reference)
#define NN   5000
#define BB   4
#define SEQ  128
#define OUTC 128
#define EE   80000
#define KTOT 384   // [X | Txo | Txi]
#define CTOT 256   // interleaved: col cc = 2*o + gate (gate 0=Z, 1=H)
#define MTOT (BB * NN)   // 20000
#define MPAD 20096       // 157 * 128
#define CAP  64          // bucket capacity; Binom(80000,1/5000) max ~40 << 64

typedef __attribute__((ext_vector_type(8))) short bf16x8;
typedef __attribute__((ext_vector_type(4))) float f32x4;

__device__ inline unsigned short f2bf(float f) {   // RNE float->bf16
    union { float f; unsigned u; } a; a.f = f;
    unsigned r = a.u + 0x7FFF + ((a.u >> 16) & 1);
    return (unsigned short)(r >> 16);
}

// ---------------------------------------------------------------------------
// Fused init: zero deg/cnt (20000 floats), fold weights into WT[cc][k] bf16
// (cc = 2*o+gate), interleave bias. W[2][2][256][128]: ((k0*2+k1)*256+r)*128+o
// ---------------------------------------------------------------------------
__global__ __launch_bounds__(256) void k_init(
        const float* __restrict__ Wz, const float* __restrict__ bz,
        const float* __restrict__ Wh, const float* __restrict__ bh,
        unsigned short* __restrict__ WT, float* __restrict__ bcat2,
        float* __restrict__ zero_region) {
    int i = blockIdx.x * blockDim.x + threadIdx.x;
    if (i < 5000) {
        f32x4 z = {0.f, 0.f, 0.f, 0.f};
        *(f32x4*)&zero_region[i * 4] = z;
    }
    if (i < CTOT) bcat2[i] = (i & 1) ? bh[i >> 1] : bz[i >> 1];
    if (i >= CTOT * KTOT) return;
    int cc = i / KTOT, k = i % KTOT;
    int gate = cc & 1, o = cc >> 1;
    const float* W = gate ? Wh : Wz;
    float v;
    if (k < 128)      v = W[(size_t)k * 128 + o] + W[(size_t)(512 + k) * 128 + o];
    else if (k < 256) v = W[(size_t)(256 + (k - 128)) * 128 + o];
    else              v = W[(size_t)(768 + (k - 256)) * 128 + o];
    WT[(size_t)cc * KTOT + k] = f2bf(v);
}

// ---------------------------------------------------------------------------
// One edge pass: weighted degrees (atomic) + fixed-stride buckets (atomic
// slot claim + int2 store). bin[d] holds (src,w) of in-edges of d; bout[s]
// holds (dst,w) of out-edges of s.
// ---------------------------------------------------------------------------
__global__ void k_bucket(const int* __restrict__ ei, const float* __restrict__ ew,
                         float* deg_out, float* deg_in,
                         unsigned* cnt_in, unsigned* cnt_out,
                         int2* __restrict__ bin, int2* __restrict__ bout) {
    int e = blockIdx.x * blockDim.x + threadIdx.x;
    if (e >= EE) return;
    int s = ei[e], d = ei[EE + e];
    float w = ew[e];
    atomicAdd(&deg_out[s], w);
    atomicAdd(&deg_in[d], w);
    unsigned p = atomicAdd(&cnt_in[d], 1u);
    if (p < CAP) bin[((size_t)d << 6) + p] = make_int2(s, __float_as_int(w));
    unsigned q = atomicAdd(&cnt_out[s], 1u);
    if (q < CAP) bout[((size_t)s << 6) + q] = make_int2(d, __float_as_int(w));
}

// ---------------------------------------------------------------------------
// Diffusion + bf16 pack of [x | Txo | Txi] into Inb[20000][384].
// One wave per (node,batch). Lists staged in wave-private LDS (padded to even
// with a cf=0 dummy). Gather: lane l serves half h=l>>5, col group q=l&31;
// each float4 load instruction fetches TWO rows (1 KB/wave). Cross-half
// reduce via shfl_xor(32). XCD-batch swizzle keeps each XCD's L2 on one
// batch's 2.56 MB x slice.
// ---------------------------------------------------------------------------
__global__ __launch_bounds__(256) void k_diffuse(
        const float* __restrict__ x,
        const float* __restrict__ deg_out, const float* __restrict__ deg_in,
        const unsigned* __restrict__ cnt_in, const unsigned* __restrict__ cnt_out,
        const int2* __restrict__ bin, const int2* __restrict__ bout,
        unsigned short* __restrict__ Inb) {
    __shared__ int2 sbA[4][CAP + 2], sbB[4][CAP + 2];
    int bid = blockIdx.x;
    int slot = bid & 7, pos = bid >> 3;
    int b = slot >> 1;
    int wv = threadIdx.x >> 6;
    int n = (pos * 2 + (slot & 1)) * 4 + wv;
    int l = threadIdx.x & 63;
    int h = l >> 5, q = l & 31;
    const float* xb = x + (size_t)b * NN * SEQ;

    f32x4 xo = *(const f32x4*)&xb[(size_t)n * SEQ + 4 * q];  // own row, issued early

    int mi = (int)min(cnt_in[n], (unsigned)CAP);
    int mo = (int)min(cnt_out[n], (unsigned)CAP);
    if (l < mi) {   // coef_o = w * dinv_out[src]
        int2 e = bin[((size_t)n << 6) + l];
        float dg = deg_out[e.x];
        float cf = dg > 0.f ? __int_as_float(e.y) / dg : 0.f;
        sbA[wv][l] = make_int2(e.x, __float_as_int(cf));
    } else if (l == mi) {
        sbA[wv][l] = make_int2(0, 0);   // pad to even
    }
    if (l < mo) {   // coef_i = w * dinv_in[dst]
        int2 e = bout[((size_t)n << 6) + l];
        float dg = deg_in[e.x];
        float cf = dg > 0.f ? __int_as_float(e.y) / dg : 0.f;
        sbB[wv][l] = make_int2(e.x, __float_as_int(cf));
    } else if (l == mo) {
        sbB[wv][l] = make_int2(0, 0);
    }
    int mie = (mi + 1) & ~1, moe = (mo + 1) & ~1;

    f32x4 ao = {0.f, 0.f, 0.f, 0.f}, ai = {0.f, 0.f, 0.f, 0.f};
    int j = 0;
    for (; j + 3 < mie; j += 4) {       // 2 pairs (4 rows) per iter
        int2 e0 = sbA[wv][j + h], e1 = sbA[wv][j + 2 + h];
        f32x4 v0 = *(const f32x4*)&xb[(size_t)e0.x * SEQ + 4 * q];
        f32x4 v1 = *(const f32x4*)&xb[(size_t)e1.x * SEQ + 4 * q];
        float c0 = __int_as_float(e0.y), c1 = __int_as_float(e1.y);
        ao.x += c0 * v0.x; ao.y += c0 * v0.y; ao.z += c0 * v0.z; ao.w += c0 * v0.w;
        ao.x += c1 * v1.x; ao.y += c1 * v1.y; ao.z += c1 * v1.z; ao.w += c1 * v1.w;
    }
    for (; j < mie; j += 2) {
        int2 e0 = sbA[wv][j + h];
        f32x4 v0 = *(const f32x4*)&xb[(size_t)e0.x * SEQ + 4 * q];
        float c0 = __int_as_float(e0.y);
        ao.x += c0 * v0.x; ao.y += c0 * v0.y; ao.z += c0 * v0.z; ao.w += c0 * v0.w;
    }
    j = 0;
    for (; j + 3 < moe; j += 4) {
        int2 e0 = sbB[wv][j + h], e1 = sbB[wv][j + 2 + h];
        f32x4 v0 = *(const f32x4*)&xb[(size_t)e0.x * SEQ + 4 * q];
        f32x4 v1 = *(const f32x4*)&xb[(size_t)e1.x * SEQ + 4 * q];
        float c0 = __int_as_float(e0.y), c1 = __int_as_float(e1.y);
        ai.x += c0 * v0.x; ai.y += c0 * v0.y; ai.z += c0 * v0.z; ai.w += c0 * v0.w;
        ai.x += c1 * v1.x; ai.y += c1 * v1.y; ai.z += c1 * v1.z; ai.w += c1 * v1.w;
    }
    for (; j < moe; j += 2) {
        int2 e0 = sbB[wv][j + h];
        f32x4 v0 = *(const f32x4*)&xb[(size_t)e0.x * SEQ + 4 * q];
        float c0 = __int_as_float(e0.y);
        ai.x += c0 * v0.x; ai.y += c0 * v0.y; ai.z += c0 * v0.z; ai.w += c0 * v0.w;
    }

    // cross-half reduction: lanes q and q+32 hold even/odd edge partial sums
    ao.x += __shfl_xor(ao.x, 32); ao.y += __shfl_xor(ao.y, 32);
    ao.z += __shfl_xor(ao.z, 32); ao.w += __shfl_xor(ao.w, 32);
    ai.x += __shfl_xor(ai.x, 32); ai.y += __shfl_xor(ai.y, 32);
    ai.z += __shfl_xor(ai.z, 32); ai.w += __shfl_xor(ai.w, 32);

    unsigned short* r = Inb + (size_t)(b * NN + n) * KTOT;
    // half 0 lanes store Txo cols (128..255), half 1 lanes store Txi (256..383)
    f32x4 av = h ? ai : ao;
    uint2 pk;
    pk.x = (unsigned)f2bf(av.x) | ((unsigned)f2bf(av.y) << 16);
    pk.y = (unsigned)f2bf(av.z) | ((unsigned)f2bf(av.w) << 16);
    *(uint2*)&r[(h ? 256 : 128) + 4 * q] = pk;
    if (!h) {  // X cols (0..127)
        uint2 px;
        px.x = (unsigned)f2bf(xo.x) | ((unsigned)f2bf(xo.y) << 16);
        px.y = (unsigned)f2bf(xo.z) | ((unsigned)f2bf(xo.w) << 16);
        *(uint2*)&r[4 * q] = px;
    }
}

// ---------------------------------------------------------------------------
// MFMA GEMM + fused epilogue, 2-phase pipelined: STAGE(next) issued before
// compute(current); one vmcnt(0)+barrier per K-step.
// D[row][cc] = sum_k Inb[row][k]*WT[cc][k]; cc=2o+gate -> shfl_xor(1) pairs
// Z/H; out = (1-sigmoid(z))*tanh(h).
// ---------------------------------------------------------------------------
__global__ __launch_bounds__(256) void k_mm(
        const unsigned short* __restrict__ Inb, const unsigned short* __restrict__ WT,
        const float* __restrict__ bcat2, float* __restrict__ out) {
    __shared__ unsigned short lA[2][4096];  // [buf][frag f*512 + lane*8]
    __shared__ unsigned short lB[2][4096];
    int t = threadIdx.x, w = t >> 6, l = t & 63;
    int lr = l & 15, lk = l >> 4;
    int n0 = blockIdx.x * 128;
    int c0 = blockIdx.y * 128;
    int wr = w >> 1, wc = w & 1;
    f32x4 acc[4][4] = {};

#define STAGE(buf, k0)                                                            \
    {                                                                             \
        _Pragma("unroll")                                                         \
        for (int qq = 0; qq < 2; ++qq) {                                          \
            int f = w * 2 + qq;                                                   \
            const unsigned short* sa = Inb + (size_t)(n0 + f * 16 + lr) * KTOT + (k0) + lk * 8; \
            __builtin_amdgcn_global_load_lds(                                     \
                (const __attribute__((address_space(1))) void*)sa,                \
                (__attribute__((address_space(3))) void*)&lA[buf][f * 512], 16, 0, 0); \
            const unsigned short* sb = WT + (size_t)(c0 + f * 16 + lr) * KTOT + (k0) + lk * 8; \
            __builtin_amdgcn_global_load_lds(                                     \
                (const __attribute__((address_space(1))) void*)sb,                \
                (__attribute__((address_space(3))) void*)&lB[buf][f * 512], 16, 0, 0); \
        }                                                                         \
    }

    STAGE(0, 0);
    asm volatile("s_waitcnt vmcnt(0)" ::: "memory");
    __builtin_amdgcn_s_barrier();

    int cur = 0;
#pragma unroll
    for (int ks = 0; ks < 12; ++ks) {
        if (ks < 11) STAGE(cur ^ 1, (ks + 1) * 32);
        bf16x8 a[4], bfr[4];
#pragma unroll
        for (int i = 0; i < 4; ++i) a[i] = *(const bf16x8*)&lA[cur][(wr * 4 + i) * 512 + l * 8];
#pragma unroll
        for (int jj = 0; jj < 4; ++jj) bfr[jj] = *(const bf16x8*)&lB[cur][(wc * 4 + jj) * 512 + l * 8];
#pragma unroll
        for (int i = 0; i < 4; ++i)
#pragma unroll
            for (int jj = 0; jj < 4; ++jj)
                acc[i][jj] = __builtin_amdgcn_mfma_f32_16x16x32_bf16(a[i], bfr[jj], acc[i][jj], 0, 0, 0);
        asm volatile("s_waitcnt vmcnt(0)" ::: "memory");
        __builtin_amdgcn_s_barrier();
        cur ^= 1;
    }
#undef STAGE

    // Epilogue: row = n0+wr*64+i*16+lk*4+rr, col cc = c0+wc*64+j*16+lr
    int row_base = n0 + wr * 64;
#pragma unroll
    for (int jj = 0; jj < 4; ++jj) {
        int cc = c0 + wc * 64 + jj * 16 + lr;
        float bias = bcat2[cc];
        int o = cc >> 1;
#pragma unroll
        for (int i = 0; i < 4; ++i) {
#pragma unroll
            for (int rr = 0; rr < 4; ++rr) {
                float v = acc[i][jj][rr] + bias;
                float p = __shfl_xor(v, 1);
                if (!(l & 1)) {
                    float z = 1.f / (1.f + __expf(-v));
                    float hh = tanhf(p);
                    int row = row_base + i * 16 + lk * 4 + rr;
                    if (row < MTOT) out[(size_t)row * OUTC + o] = (1.f - z) * hh;
                }
            }
        }
    }
}

// ---------------------------------------------------------------------------
extern "C" void kernel_launch(void* const* d_in, const int* in_sizes, int n_in,
                              void* d_out, int out_size, void* d_ws, size_t ws_size,
                              hipStream_t stream) {
    const float* x  = (const float*)d_in[0];
    const int*   ei = (const int*)d_in[1];
    const float* ew = (const float*)d_in[2];
    const float* Wz = (const float*)d_in[3];
    const float* bz = (const float*)d_in[4];
    // d_in[5]=Wr, d_in[6]=br dead (H0==0 -> Xc2==Xc, R unused)
    const float* Wh = (const float*)d_in[7];
    const float* bh = (const float*)d_in[8];

    float* ws = (float*)d_ws;
    float*    deg_out = ws + 0;                        // 5000
    float*    deg_in  = ws + 5000;                     // 5000
    unsigned* cnt_in  = (unsigned*)(ws + 10000);       // 5000
    unsigned* cnt_out = (unsigned*)(ws + 15000);       // 5000
    float*    bcat2   = ws + 20000;                    // 256
    unsigned short* WT = (unsigned short*)(ws + 20256);  // 256*384 bf16 (49152 fl)
    int2*     bin  = (int2*)(ws + 69408);              // 5000*64 int2 (640000 fl)
    int2*     bout = (int2*)(ws + 709408);             // 5000*64 int2 (640000 fl)
    unsigned short* Inb = (unsigned short*)(ws + 1349408);  // MPAD*384 bf16

    k_init<<<(CTOT * KTOT + 255) / 256, 256, 0, stream>>>(Wz, bz, Wh, bh, WT, bcat2, ws);
    k_bucket<<<(EE + 255) / 256, 256, 0, stream>>>(ei, ew, deg_out, deg_in,
                                                   cnt_in, cnt_out, bin, bout);
    k_diffuse<<<NN, 256, 0, stream>>>(x, deg_out, deg_in, cnt_in, cnt_out, bin, bout, Inb);
    dim3 g(MPAD / 128, 2);
    k_mm<<<g, 256, 0, stream>>>(Inb, WT, bcat2, (float*)d_out);
}

// Round 6
// 77.794 us; speedup vs baseline: 2.3340x; 1.0466x over previous
//
#include <hip/hip_runtime.h>
#include <math.h>

// Problem constants (fixed by the reference)
#define NN   5000
#define BB   4
#define SEQ  128
#define OUTC 128
#define EE   80000
#define KTOT 384   // [X | Txo | Txi]
#define CTOT 256   // interleaved: col cc = 2*o + gate (gate 0=Z, 1=H)
#define MTOT (BB * NN)   // 20000
#define MPAD 20096       // 157 * 128
#define CAP  64          // bucket capacity; Binom(80000,1/5000) max ~40 << 64
#define EBLK 313         // ceil(EE/256)

typedef __attribute__((ext_vector_type(8))) short bf16x8;
typedef __attribute__((ext_vector_type(4))) float f32x4;

__device__ inline unsigned short f2bf(float f) {   // RNE float->bf16
    union { float f; unsigned u; } a; a.f = f;
    unsigned r = a.u + 0x7FFF + ((a.u >> 16) & 1);
    return (unsigned short)(r >> 16);
}

// ---------------------------------------------------------------------------
// Zero deg/cnt region: 20000 floats. Tiny (20 blocks) — must precede bucket.
// ---------------------------------------------------------------------------
__global__ __launch_bounds__(256) void k_zero(float* __restrict__ z) {
    int i = blockIdx.x * blockDim.x + threadIdx.x;
    if (i < 5000) {
        f32x4 zz = {0.f, 0.f, 0.f, 0.f};
        *(f32x4*)&z[i * 4] = zz;
    }
}

// ---------------------------------------------------------------------------
// Edge pass + weight fold in one launch (block-uniform branch; fold blocks
// run concurrently with the atomic-heavy edge blocks).
// Edges: weighted degrees (atomic) + fixed-stride buckets. bin[d] = (src,w)
// in-edges of d; bout[s] = (dst,w) out-edges of s.
// Fold: WT[cc][k] bf16, cc = 2*o+gate; k<128: W[0,0]+W[1,0] (H0 rows dead);
// 128-255: W[0,1]; 256-383: W[1,1]. W[2][2][256][128]: ((k0*2+k1)*256+r)*128+o
// ---------------------------------------------------------------------------
__global__ __launch_bounds__(256) void k_bucket_fold(
        const int* __restrict__ ei, const float* __restrict__ ew,
        const float* __restrict__ Wz, const float* __restrict__ bz,
        const float* __restrict__ Wh, const float* __restrict__ bh,
        float* deg_out, float* deg_in,
        unsigned* cnt_in, unsigned* cnt_out,
        int2* __restrict__ bin, int2* __restrict__ bout,
        unsigned short* __restrict__ WT, float* __restrict__ bcat2) {
    int bid = blockIdx.x;
    if (bid < EBLK) {
        int e = bid * 256 + threadIdx.x;
        if (e >= EE) return;
        int s = ei[e], d = ei[EE + e];
        float w = ew[e];
        atomicAdd(&deg_out[s], w);
        atomicAdd(&deg_in[d], w);
        unsigned p = atomicAdd(&cnt_in[d], 1u);
        if (p < CAP) bin[((size_t)d << 6) + p] = make_int2(s, __float_as_int(w));
        unsigned q = atomicAdd(&cnt_out[s], 1u);
        if (q < CAP) bout[((size_t)s << 6) + q] = make_int2(d, __float_as_int(w));
    } else {
        int i = (bid - EBLK) * 256 + threadIdx.x;   // [0, CTOT*KTOT)
        if (i < CTOT) bcat2[i] = (i & 1) ? bh[i >> 1] : bz[i >> 1];
        int cc = i / KTOT, k = i % KTOT;
        int gate = cc & 1, o = cc >> 1;
        const float* W = gate ? Wh : Wz;
        float v;
        if (k < 128)      v = W[(size_t)k * 128 + o] + W[(size_t)(512 + k) * 128 + o];
        else if (k < 256) v = W[(size_t)(256 + (k - 128)) * 128 + o];
        else              v = W[(size_t)(768 + (k - 256)) * 128 + o];
        WT[(size_t)cc * KTOT + k] = f2bf(v);
    }
}

// ---------------------------------------------------------------------------
// Diffusion + bf16 pack of [x | Txo | Txi] into Inb[20000][384].
// One wave per (node,batch). Lists staged in wave-private LDS (padded to even
// with a cf=0 dummy). Gather: lane l serves half h=l>>5, col group q=l&31;
// each float4 load fetches TWO rows (1 KB/wave). Cross-half reduce via
// shfl_xor(32). XCD-batch swizzle keeps each XCD's L2 on one batch's x slice.
// ---------------------------------------------------------------------------
__global__ __launch_bounds__(256) void k_diffuse(
        const float* __restrict__ x,
        const float* __restrict__ deg_out, const float* __restrict__ deg_in,
        const unsigned* __restrict__ cnt_in, const unsigned* __restrict__ cnt_out,
        const int2* __restrict__ bin, const int2* __restrict__ bout,
        unsigned short* __restrict__ Inb) {
    __shared__ int2 sbA[4][CAP + 2], sbB[4][CAP + 2];
    int bid = blockIdx.x;
    int slot = bid & 7, pos = bid >> 3;
    int b = slot >> 1;
    int wv = threadIdx.x >> 6;
    int n = (pos * 2 + (slot & 1)) * 4 + wv;
    int l = threadIdx.x & 63;
    int h = l >> 5, q = l & 31;
    const float* xb = x + (size_t)b * NN * SEQ;

    f32x4 xo = *(const f32x4*)&xb[(size_t)n * SEQ + 4 * q];  // own row, issued early

    int mi = (int)min(cnt_in[n], (unsigned)CAP);
    int mo = (int)min(cnt_out[n], (unsigned)CAP);
    if (l < mi) {   // coef_o = w * dinv_out[src]
        int2 e = bin[((size_t)n << 6) + l];
        float dg = deg_out[e.x];
        float cf = dg > 0.f ? __int_as_float(e.y) / dg : 0.f;
        sbA[wv][l] = make_int2(e.x, __float_as_int(cf));
    } else if (l == mi) {
        sbA[wv][l] = make_int2(0, 0);   // pad to even
    }
    if (l < mo) {   // coef_i = w * dinv_in[dst]
        int2 e = bout[((size_t)n << 6) + l];
        float dg = deg_in[e.x];
        float cf = dg > 0.f ? __int_as_float(e.y) / dg : 0.f;
        sbB[wv][l] = make_int2(e.x, __float_as_int(cf));
    } else if (l == mo) {
        sbB[wv][l] = make_int2(0, 0);
    }
    int mie = (mi + 1) & ~1, moe = (mo + 1) & ~1;

    f32x4 ao = {0.f, 0.f, 0.f, 0.f}, ai = {0.f, 0.f, 0.f, 0.f};
    int j = 0;
    for (; j + 3 < mie; j += 4) {       // 2 pairs (4 rows) per iter
        int2 e0 = sbA[wv][j + h], e1 = sbA[wv][j + 2 + h];
        f32x4 v0 = *(const f32x4*)&xb[(size_t)e0.x * SEQ + 4 * q];
        f32x4 v1 = *(const f32x4*)&xb[(size_t)e1.x * SEQ + 4 * q];
        float c0 = __int_as_float(e0.y), c1 = __int_as_float(e1.y);
        ao.x += c0 * v0.x; ao.y += c0 * v0.y; ao.z += c0 * v0.z; ao.w += c0 * v0.w;
        ao.x += c1 * v1.x; ao.y += c1 * v1.y; ao.z += c1 * v1.z; ao.w += c1 * v1.w;
    }
    for (; j < mie; j += 2) {
        int2 e0 = sbA[wv][j + h];
        f32x4 v0 = *(const f32x4*)&xb[(size_t)e0.x * SEQ + 4 * q];
        float c0 = __int_as_float(e0.y);
        ao.x += c0 * v0.x; ao.y += c0 * v0.y; ao.z += c0 * v0.z; ao.w += c0 * v0.w;
    }
    j = 0;
    for (; j + 3 < moe; j += 4) {
        int2 e0 = sbB[wv][j + h], e1 = sbB[wv][j + 2 + h];
        f32x4 v0 = *(const f32x4*)&xb[(size_t)e0.x * SEQ + 4 * q];
        f32x4 v1 = *(const f32x4*)&xb[(size_t)e1.x * SEQ + 4 * q];
        float c0 = __int_as_float(e0.y), c1 = __int_as_float(e1.y);
        ai.x += c0 * v0.x; ai.y += c0 * v0.y; ai.z += c0 * v0.z; ai.w += c0 * v0.w;
        ai.x += c1 * v1.x; ai.y += c1 * v1.y; ai.z += c1 * v1.z; ai.w += c1 * v1.w;
    }
    for (; j < moe; j += 2) {
        int2 e0 = sbB[wv][j + h];
        f32x4 v0 = *(const f32x4*)&xb[(size_t)e0.x * SEQ + 4 * q];
        float c0 = __int_as_float(e0.y);
        ai.x += c0 * v0.x; ai.y += c0 * v0.y; ai.z += c0 * v0.z; ai.w += c0 * v0.w;
    }

    // cross-half reduction: lanes q and q+32 hold even/odd edge partial sums
    ao.x += __shfl_xor(ao.x, 32); ao.y += __shfl_xor(ao.y, 32);
    ao.z += __shfl_xor(ao.z, 32); ao.w += __shfl_xor(ao.w, 32);
    ai.x += __shfl_xor(ai.x, 32); ai.y += __shfl_xor(ai.y, 32);
    ai.z += __shfl_xor(ai.z, 32); ai.w += __shfl_xor(ai.w, 32);

    unsigned short* r = Inb + (size_t)(b * NN + n) * KTOT;
    // half 0 lanes store Txo cols (128..255), half 1 lanes store Txi (256..383)
    f32x4 av = h ? ai : ao;
    uint2 pk;
    pk.x = (unsigned)f2bf(av.x) | ((unsigned)f2bf(av.y) << 16);
    pk.y = (unsigned)f2bf(av.z) | ((unsigned)f2bf(av.w) << 16);
    *(uint2*)&r[(h ? 256 : 128) + 4 * q] = pk;
    if (!h) {  // X cols (0..127)
        uint2 px;
        px.x = (unsigned)f2bf(xo.x) | ((unsigned)f2bf(xo.y) << 16);
        px.y = (unsigned)f2bf(xo.z) | ((unsigned)f2bf(xo.w) << 16);
        *(uint2*)&r[4 * q] = px;
    }
}

// ---------------------------------------------------------------------------
// MFMA GEMM + fused epilogue, 2-phase pipelined: STAGE(next) issued before
// compute(current); one vmcnt(0)+barrier per K-step.
// D[row][cc] = sum_k Inb[row][k]*WT[cc][k]; cc=2o+gate. Epilogue: even lane
// computes 1-sigmoid(z) = 1/(1+e^z), odd lane computes tanh(h) = 1-2/(e^2h+1)
// (one v_exp + v_rcp per lane, no libm, no idle half-wave); shfl_xor(1)
// combines; out = (1-Z)*tanh(H).
// ---------------------------------------------------------------------------
__global__ __launch_bounds__(256) void k_mm(
        const unsigned short* __restrict__ Inb, const unsigned short* __restrict__ WT,
        const float* __restrict__ bcat2, float* __restrict__ out) {
    __shared__ unsigned short lA[2][4096];  // [buf][frag f*512 + lane*8]
    __shared__ unsigned short lB[2][4096];
    int t = threadIdx.x, w = t >> 6, l = t & 63;
    int lr = l & 15, lk = l >> 4;
    int n0 = blockIdx.x * 128;
    int c0 = blockIdx.y * 128;
    int wr = w >> 1, wc = w & 1;
    f32x4 acc[4][4] = {};

#define STAGE(buf, k0)                                                            \
    {                                                                             \
        _Pragma("unroll")                                                         \
        for (int qq = 0; qq < 2; ++qq) {                                          \
            int f = w * 2 + qq;                                                   \
            const unsigned short* sa = Inb + (size_t)(n0 + f * 16 + lr) * KTOT + (k0) + lk * 8; \
            __builtin_amdgcn_global_load_lds(                                     \
                (const __attribute__((address_space(1))) void*)sa,                \
                (__attribute__((address_space(3))) void*)&lA[buf][f * 512], 16, 0, 0); \
            const unsigned short* sb = WT + (size_t)(c0 + f * 16 + lr) * KTOT + (k0) + lk * 8; \
            __builtin_amdgcn_global_load_lds(                                     \
                (const __attribute__((address_space(1))) void*)sb,                \
                (__attribute__((address_space(3))) void*)&lB[buf][f * 512], 16, 0, 0); \
        }                                                                         \
    }

    STAGE(0, 0);
    asm volatile("s_waitcnt vmcnt(0)" ::: "memory");
    __builtin_amdgcn_s_barrier();

    int cur = 0;
#pragma unroll
    for (int ks = 0; ks < 12; ++ks) {
        if (ks < 11) STAGE(cur ^ 1, (ks + 1) * 32);
        bf16x8 a[4], bfr[4];
#pragma unroll
        for (int i = 0; i < 4; ++i) a[i] = *(const bf16x8*)&lA[cur][(wr * 4 + i) * 512 + l * 8];
#pragma unroll
        for (int jj = 0; jj < 4; ++jj) bfr[jj] = *(const bf16x8*)&lB[cur][(wc * 4 + jj) * 512 + l * 8];
#pragma unroll
        for (int i = 0; i < 4; ++i)
#pragma unroll
            for (int jj = 0; jj < 4; ++jj)
                acc[i][jj] = __builtin_amdgcn_mfma_f32_16x16x32_bf16(a[i], bfr[jj], acc[i][jj], 0, 0, 0);
        asm volatile("s_waitcnt vmcnt(0)" ::: "memory");
        __builtin_amdgcn_s_barrier();
        cur ^= 1;
    }
#undef STAGE

    // Epilogue: row = n0+wr*64+i*16+lk*4+rr, col cc = c0+wc*64+jj*16+lr
    int row_base = n0 + wr * 64;
    bool odd = (l & 1);
#pragma unroll
    for (int jj = 0; jj < 4; ++jj) {
        int cc = c0 + wc * 64 + jj * 16 + lr;
        float bias = bcat2[cc];
        int o = cc >> 1;
#pragma unroll
        for (int i = 0; i < 4; ++i) {
#pragma unroll
            for (int rr = 0; rr < 4; ++rr) {
                float v = acc[i][jj][rr] + bias;
                // even lane (v = z_pre): u = 1/(1+e^v)   = 1 - sigmoid(v)
                // odd  lane (v = h_pre): u = 1-2/(e^2v+1) = tanh(v)
                float ex = __expf(odd ? 2.f * v : v);
                float u = odd ? (1.f - 2.f / (ex + 1.f)) : (1.f / (1.f + ex));
                float g = __shfl_xor(u, 1);
                if (!odd) {
                    int row = row_base + i * 16 + lk * 4 + rr;
                    if (row < MTOT) out[(size_t)row * OUTC + o] = u * g;
                }
            }
        }
    }
}

// ---------------------------------------------------------------------------
extern "C" void kernel_launch(void* const* d_in, const int* in_sizes, int n_in,
                              void* d_out, int out_size, void* d_ws, size_t ws_size,
                              hipStream_t stream) {
    const float* x  = (const float*)d_in[0];
    const int*   ei = (const int*)d_in[1];
    const float* ew = (const float*)d_in[2];
    const float* Wz = (const float*)d_in[3];
    const float* bz = (const float*)d_in[4];
    // d_in[5]=Wr, d_in[6]=br dead (H0==0 -> Xc2==Xc, R unused)
    const float* Wh = (const float*)d_in[7];
    const float* bh = (const float*)d_in[8];

    float* ws = (float*)d_ws;
    float*    deg_out = ws + 0;                        // 5000
    float*    deg_in  = ws + 5000;                     // 5000
    unsigned* cnt_in  = (unsigned*)(ws + 10000);       // 5000
    unsigned* cnt_out = (unsigned*)(ws + 15000);       // 5000
    float*    bcat2   = ws + 20000;                    // 256
    unsigned short* WT = (unsigned short*)(ws + 20256);  // 256*384 bf16 (49152 fl)
    int2*     bin  = (int2*)(ws + 69408);              // 5000*64 int2 (640000 fl)
    int2*     bout = (int2*)(ws + 709408);             // 5000*64 int2 (640000 fl)
    unsigned short* Inb = (unsigned short*)(ws + 1349408);  // MPAD*384 bf16

    k_zero<<<20, 256, 0, stream>>>(ws);
    k_bucket_fold<<<EBLK + CTOT * KTOT / 256, 256, 0, stream>>>(
        ei, ew, Wz, bz, Wh, bh, deg_out, deg_in, cnt_in, cnt_out, bin, bout, WT, bcat2);
    k_diffuse<<<NN, 256, 0, stream>>>(x, deg_out, deg_in, cnt_in, cnt_out, bin, bout, Inb);
    dim3 g(MPAD / 128, 2);
    k_mm<<<g, 256, 0, stream>>>(Inb, WT, bcat2, (float*)d_out);
}

// Round 7
// 75.194 us; speedup vs baseline: 2.4147x; 1.0346x over previous
//
#include <hip/hip_runtime.h>
#include <math.h>

// Problem constants (fixed by the reference)
#define NN   5000
#define BB   4
#define SEQ  128
#define OUTC 128
#define EE   80000
#define KTOT 384   // [X | Txo | Txi]
#define CTOT 256   // interleaved: col cc = 2*o + gate (gate 0=Z, 1=H)
#define MTOT (BB * NN)   // 20000
#define MPAD 20096       // 157 * 128
#define CAP  64          // bucket capacity; Binom(80000,1/5000) max ~40 << 64
#define EBLK 313         // ceil(EE/256)
#define FBLK 384         // CTOT*KTOT/256 weight-fold blocks
#define XBLK 1250        // x->bf16 convert blocks (320000 threads x 8 elems)

typedef __attribute__((ext_vector_type(8))) short bf16x8;
typedef __attribute__((ext_vector_type(4))) float f32x4;

__device__ inline unsigned short f2bf(float f) {   // RNE float->bf16
    union { float f; unsigned u; } a; a.f = f;
    unsigned r = a.u + 0x7FFF + ((a.u >> 16) & 1);
    return (unsigned short)(r >> 16);
}

// ---------------------------------------------------------------------------
// Zero deg/cnt region: 20000 floats.
// ---------------------------------------------------------------------------
__global__ __launch_bounds__(256) void k_zero(float* __restrict__ z) {
    int i = blockIdx.x * blockDim.x + threadIdx.x;
    if (i < 5000) {
        f32x4 zz = {0.f, 0.f, 0.f, 0.f};
        *(f32x4*)&z[i * 4] = zz;
    }
}

// ---------------------------------------------------------------------------
// One launch, three block roles (block-uniform branch):
//  [0,EBLK): edge pass — weighted degrees (atomic) + fixed-stride buckets.
//  [EBLK,EBLK+FBLK): weight fold WT[cc][k] bf16 (cc=2o+gate) + bias.
//  [EBLK+FBLK,..+XBLK): x -> bf16 copy (xb16), 8 elems/thread.
// ---------------------------------------------------------------------------
__global__ __launch_bounds__(256) void k_bucket_fold(
        const int* __restrict__ ei, const float* __restrict__ ew,
        const float* __restrict__ x,
        const float* __restrict__ Wz, const float* __restrict__ bz,
        const float* __restrict__ Wh, const float* __restrict__ bh,
        float* deg_out, float* deg_in,
        unsigned* cnt_in, unsigned* cnt_out,
        int2* __restrict__ bin, int2* __restrict__ bout,
        unsigned short* __restrict__ WT, float* __restrict__ bcat2,
        unsigned short* __restrict__ xb16) {
    int bid = blockIdx.x;
    if (bid < EBLK) {
        int e = bid * 256 + threadIdx.x;
        if (e >= EE) return;
        int s = ei[e], d = ei[EE + e];
        float w = ew[e];
        atomicAdd(&deg_out[s], w);
        atomicAdd(&deg_in[d], w);
        unsigned p = atomicAdd(&cnt_in[d], 1u);
        if (p < CAP) bin[((size_t)d << 6) + p] = make_int2(s, __float_as_int(w));
        unsigned q = atomicAdd(&cnt_out[s], 1u);
        if (q < CAP) bout[((size_t)s << 6) + q] = make_int2(d, __float_as_int(w));
    } else if (bid < EBLK + FBLK) {
        int i = (bid - EBLK) * 256 + threadIdx.x;   // [0, CTOT*KTOT)
        if (i < CTOT) bcat2[i] = (i & 1) ? bh[i >> 1] : bz[i >> 1];
        int cc = i / KTOT, k = i % KTOT;
        int gate = cc & 1, o = cc >> 1;
        const float* W = gate ? Wh : Wz;
        float v;
        if (k < 128)      v = W[(size_t)k * 128 + o] + W[(size_t)(512 + k) * 128 + o];
        else if (k < 256) v = W[(size_t)(256 + (k - 128)) * 128 + o];
        else              v = W[(size_t)(768 + (k - 256)) * 128 + o];
        WT[(size_t)cc * KTOT + k] = f2bf(v);
    } else {
        int j = (bid - EBLK - FBLK) * 256 + threadIdx.x;   // [0, 320000)
        if (j < (BB * NN * SEQ) / 8) {
            const float4* xp = (const float4*)x;
            float4 v0 = xp[(size_t)j * 2], v1 = xp[(size_t)j * 2 + 1];
            uint4 pk;
            pk.x = (unsigned)f2bf(v0.x) | ((unsigned)f2bf(v0.y) << 16);
            pk.y = (unsigned)f2bf(v0.z) | ((unsigned)f2bf(v0.w) << 16);
            pk.z = (unsigned)f2bf(v1.x) | ((unsigned)f2bf(v1.y) << 16);
            pk.w = (unsigned)f2bf(v1.z) | ((unsigned)f2bf(v1.w) << 16);
            ((uint4*)xb16)[j] = pk;
        }
    }
}

// ---------------------------------------------------------------------------
// Diffusion from bf16 x. One wave per (node,batch). Lane l: slot h=l>>4
// (row j+h), col group q=l&15 (8 cols). One uint4 load = 8 bf16 cols; a
// wave-load covers 4 rows x 128 cols (1 KB). Lists staged in wave-private
// LDS padded to multiple of 4 with cf=0 dummies. Cross-slot reduce via
// shfl_xor(16/32). Store roles: h=0 Txo, h=1 Txi, h=2 X-copy.
// XCD-batch swizzle: blockIdx&7 -> each XCD's L2 holds one batch's x slice.
// ---------------------------------------------------------------------------
#define ACC8(A, v, cf) {                                              \
    A[0] += (cf) * __uint_as_float((v).x << 16);                      \
    A[1] += (cf) * __uint_as_float((v).x & 0xFFFF0000u);              \
    A[2] += (cf) * __uint_as_float((v).y << 16);                      \
    A[3] += (cf) * __uint_as_float((v).y & 0xFFFF0000u);              \
    A[4] += (cf) * __uint_as_float((v).z << 16);                      \
    A[5] += (cf) * __uint_as_float((v).z & 0xFFFF0000u);              \
    A[6] += (cf) * __uint_as_float((v).w << 16);                      \
    A[7] += (cf) * __uint_as_float((v).w & 0xFFFF0000u); }

__global__ __launch_bounds__(256) void k_diffuse(
        const unsigned short* __restrict__ xb16,
        const float* __restrict__ deg_out, const float* __restrict__ deg_in,
        const unsigned* __restrict__ cnt_in, const unsigned* __restrict__ cnt_out,
        const int2* __restrict__ bin, const int2* __restrict__ bout,
        unsigned short* __restrict__ Inb) {
    __shared__ int2 sbA[4][CAP + 4], sbB[4][CAP + 4];
    int bid = blockIdx.x;
    int slot = bid & 7, pos = bid >> 3;
    int b = slot >> 1;
    int wv = threadIdx.x >> 6;
    int n = (pos * 2 + (slot & 1)) * 4 + wv;
    int l = threadIdx.x & 63;
    int h = l >> 4, q = l & 15;
    const unsigned short* xb = xb16 + (size_t)b * NN * SEQ;

    int mi = (int)min(cnt_in[n], (unsigned)CAP);
    int mo = (int)min(cnt_out[n], (unsigned)CAP);
    if (l < mi) {   // coef_o = w * dinv_out[src]
        int2 e = bin[((size_t)n << 6) + l];
        float dg = deg_out[e.x];
        float cf = dg > 0.f ? __int_as_float(e.y) / dg : 0.f;
        sbA[wv][l] = make_int2(e.x, __float_as_int(cf));
    } else if (l < ((mi + 3) & ~3)) {
        sbA[wv][l] = make_int2(0, 0);   // pad to multiple of 4
    }
    if (l < mo) {   // coef_i = w * dinv_in[dst]
        int2 e = bout[((size_t)n << 6) + l];
        float dg = deg_in[e.x];
        float cf = dg > 0.f ? __int_as_float(e.y) / dg : 0.f;
        sbB[wv][l] = make_int2(e.x, __float_as_int(cf));
    } else if (l < ((mo + 3) & ~3)) {
        sbB[wv][l] = make_int2(0, 0);
    }
    int mie = (mi + 3) & ~3, moe = (mo + 3) & ~3;

    float ao[8] = {0.f, 0.f, 0.f, 0.f, 0.f, 0.f, 0.f, 0.f};
    float ai[8] = {0.f, 0.f, 0.f, 0.f, 0.f, 0.f, 0.f, 0.f};
    int j = 0;
    for (; j + 7 < mie; j += 8) {   // 2 loads in flight
        int2 e0 = sbA[wv][j + h], e1 = sbA[wv][j + 4 + h];
        uint4 v0 = *(const uint4*)&xb[(size_t)e0.x * SEQ + 8 * q];
        uint4 v1 = *(const uint4*)&xb[(size_t)e1.x * SEQ + 8 * q];
        float c0 = __int_as_float(e0.y), c1 = __int_as_float(e1.y);
        ACC8(ao, v0, c0);
        ACC8(ao, v1, c1);
    }
    for (; j < mie; j += 4) {
        int2 e0 = sbA[wv][j + h];
        uint4 v0 = *(const uint4*)&xb[(size_t)e0.x * SEQ + 8 * q];
        float c0 = __int_as_float(e0.y);
        ACC8(ao, v0, c0);
    }
    j = 0;
    for (; j + 7 < moe; j += 8) {
        int2 e0 = sbB[wv][j + h], e1 = sbB[wv][j + 4 + h];
        uint4 v0 = *(const uint4*)&xb[(size_t)e0.x * SEQ + 8 * q];
        uint4 v1 = *(const uint4*)&xb[(size_t)e1.x * SEQ + 8 * q];
        float c0 = __int_as_float(e0.y), c1 = __int_as_float(e1.y);
        ACC8(ai, v0, c0);
        ACC8(ai, v1, c1);
    }
    for (; j < moe; j += 4) {
        int2 e0 = sbB[wv][j + h];
        uint4 v0 = *(const uint4*)&xb[(size_t)e0.x * SEQ + 8 * q];
        float c0 = __int_as_float(e0.y);
        ACC8(ai, v0, c0);
    }

    // reduce over the 4 row-slots (lanes l, l^16, l^32, l^48)
#pragma unroll
    for (int r = 0; r < 8; ++r) {
        ao[r] += __shfl_xor(ao[r], 16); ao[r] += __shfl_xor(ao[r], 32);
        ai[r] += __shfl_xor(ai[r], 16); ai[r] += __shfl_xor(ai[r], 32);
    }

    unsigned short* rw = Inb + (size_t)(b * NN + n) * KTOT;
    if (h == 0) {          // Txo cols 128..255
        uint4 pk;
        pk.x = (unsigned)f2bf(ao[0]) | ((unsigned)f2bf(ao[1]) << 16);
        pk.y = (unsigned)f2bf(ao[2]) | ((unsigned)f2bf(ao[3]) << 16);
        pk.z = (unsigned)f2bf(ao[4]) | ((unsigned)f2bf(ao[5]) << 16);
        pk.w = (unsigned)f2bf(ao[6]) | ((unsigned)f2bf(ao[7]) << 16);
        *(uint4*)&rw[128 + 8 * q] = pk;
    } else if (h == 1) {   // Txi cols 256..383
        uint4 pk;
        pk.x = (unsigned)f2bf(ai[0]) | ((unsigned)f2bf(ai[1]) << 16);
        pk.y = (unsigned)f2bf(ai[2]) | ((unsigned)f2bf(ai[3]) << 16);
        pk.z = (unsigned)f2bf(ai[4]) | ((unsigned)f2bf(ai[5]) << 16);
        pk.w = (unsigned)f2bf(ai[6]) | ((unsigned)f2bf(ai[7]) << 16);
        *(uint4*)&rw[256 + 8 * q] = pk;
    } else if (h == 2) {   // X copy cols 0..127
        uint4 xv = *(const uint4*)&xb[(size_t)n * SEQ + 8 * q];
        *(uint4*)&rw[8 * q] = xv;
    }
}

// ---------------------------------------------------------------------------
// MFMA GEMM + fused epilogue. 3-buffer pipeline with counted vmcnt (T4):
// steady-state s_waitcnt vmcnt(4) waits only the 2-steps-old stage's 4
// global_load_lds; one barrier per K-step; stage k+2 issued after compute(k)
// into the buffer last read at step k-1 (all waves past barrier k -> safe).
// Epilogue: even lane 1/(1+e^z)=1-sigm, odd lane tanh via e^2h; shfl_xor(1).
// ---------------------------------------------------------------------------
__global__ __launch_bounds__(256) void k_mm(
        const unsigned short* __restrict__ Inb, const unsigned short* __restrict__ WT,
        const float* __restrict__ bcat2, float* __restrict__ out) {
    __shared__ unsigned short lA[3][4096];  // [buf][frag f*512 + lane*8]
    __shared__ unsigned short lB[3][4096];
    int t = threadIdx.x, w = t >> 6, l = t & 63;
    int lr = l & 15, lk = l >> 4;
    int n0 = blockIdx.x * 128;
    int c0 = blockIdx.y * 128;
    int wr = w >> 1, wc = w & 1;
    f32x4 acc[4][4] = {};

#define STAGE(buf, k0)                                                            \
    {                                                                             \
        _Pragma("unroll")                                                         \
        for (int qq = 0; qq < 2; ++qq) {                                          \
            int f = w * 2 + qq;                                                   \
            const unsigned short* sa = Inb + (size_t)(n0 + f * 16 + lr) * KTOT + (k0) + lk * 8; \
            __builtin_amdgcn_global_load_lds(                                     \
                (const __attribute__((address_space(1))) void*)sa,                \
                (__attribute__((address_space(3))) void*)&lA[buf][f * 512], 16, 0, 0); \
            const unsigned short* sb = WT + (size_t)(c0 + f * 16 + lr) * KTOT + (k0) + lk * 8; \
            __builtin_amdgcn_global_load_lds(                                     \
                (const __attribute__((address_space(1))) void*)sb,                \
                (__attribute__((address_space(3))) void*)&lB[buf][f * 512], 16, 0, 0); \
        }                                                                         \
    }

    STAGE(0, 0);
    STAGE(1, 32);

#pragma unroll
    for (int ks = 0; ks < 12; ++ks) {
        if (ks < 11) asm volatile("s_waitcnt vmcnt(4)" ::: "memory");
        else         asm volatile("s_waitcnt vmcnt(0)" ::: "memory");
        __builtin_amdgcn_s_barrier();
        const int bf = ks % 3;
        bf16x8 a[4], bfr[4];
#pragma unroll
        for (int i = 0; i < 4; ++i) a[i] = *(const bf16x8*)&lA[bf][(wr * 4 + i) * 512 + l * 8];
#pragma unroll
        for (int jj = 0; jj < 4; ++jj) bfr[jj] = *(const bf16x8*)&lB[bf][(wc * 4 + jj) * 512 + l * 8];
#pragma unroll
        for (int i = 0; i < 4; ++i)
#pragma unroll
            for (int jj = 0; jj < 4; ++jj)
                acc[i][jj] = __builtin_amdgcn_mfma_f32_16x16x32_bf16(a[i], bfr[jj], acc[i][jj], 0, 0, 0);
        if (ks + 2 < 12) STAGE((ks + 2) % 3, (ks + 2) * 32);
    }
#undef STAGE

    // Epilogue: row = n0+wr*64+i*16+lk*4+rr, col cc = c0+wc*64+jj*16+lr
    int row_base = n0 + wr * 64;
    bool odd = (l & 1);
#pragma unroll
    for (int jj = 0; jj < 4; ++jj) {
        int cc = c0 + wc * 64 + jj * 16 + lr;
        float bias = bcat2[cc];
        int o = cc >> 1;
#pragma unroll
        for (int i = 0; i < 4; ++i) {
#pragma unroll
            for (int rr = 0; rr < 4; ++rr) {
                float v = acc[i][jj][rr] + bias;
                // even lane (v=z_pre): u = 1/(1+e^v)    = 1 - sigmoid(v)
                // odd  lane (v=h_pre): u = 1-2/(e^2v+1) = tanh(v)
                float ex = __expf(odd ? 2.f * v : v);
                float u = odd ? (1.f - 2.f / (ex + 1.f)) : (1.f / (1.f + ex));
                float g = __shfl_xor(u, 1);
                if (!odd) {
                    int row = row_base + i * 16 + lk * 4 + rr;
                    if (row < MTOT) out[(size_t)row * OUTC + o] = u * g;
                }
            }
        }
    }
}

// ---------------------------------------------------------------------------
extern "C" void kernel_launch(void* const* d_in, const int* in_sizes, int n_in,
                              void* d_out, int out_size, void* d_ws, size_t ws_size,
                              hipStream_t stream) {
    const float* x  = (const float*)d_in[0];
    const int*   ei = (const int*)d_in[1];
    const float* ew = (const float*)d_in[2];
    const float* Wz = (const float*)d_in[3];
    const float* bz = (const float*)d_in[4];
    // d_in[5]=Wr, d_in[6]=br dead (H0==0 -> Xc2==Xc, R unused)
    const float* Wh = (const float*)d_in[7];
    const float* bh = (const float*)d_in[8];

    float* ws = (float*)d_ws;
    float*    deg_out = ws + 0;                        // 5000
    float*    deg_in  = ws + 5000;                     // 5000
    unsigned* cnt_in  = (unsigned*)(ws + 10000);       // 5000
    unsigned* cnt_out = (unsigned*)(ws + 15000);       // 5000
    float*    bcat2   = ws + 20000;                    // 256
    unsigned short* WT = (unsigned short*)(ws + 20256);  // 256*384 bf16 (49152 fl)
    int2*     bin  = (int2*)(ws + 69408);              // 5000*64 int2 (640000 fl)
    int2*     bout = (int2*)(ws + 709408);             // 5000*64 int2 (640000 fl)
    unsigned short* xb16 = (unsigned short*)(ws + 1349408); // 2.56M bf16 (1.28M fl)
    unsigned short* Inb = (unsigned short*)(ws + 2629408);  // MPAD*384 bf16

    k_zero<<<20, 256, 0, stream>>>(ws);
    k_bucket_fold<<<EBLK + FBLK + XBLK, 256, 0, stream>>>(
        ei, ew, x, Wz, bz, Wh, bh, deg_out, deg_in, cnt_in, cnt_out,
        bin, bout, WT, bcat2, xb16);
    k_diffuse<<<NN, 256, 0, stream>>>(xb16, deg_out, deg_in, cnt_in, cnt_out,
                                      bin, bout, Inb);
    dim3 g(MPAD / 128, 2);
    k_mm<<<g, 256, 0, stream>>>(Inb, WT, bcat2, (float*)d_out);
}

// Round 8
// 72.638 us; speedup vs baseline: 2.4997x; 1.0352x over previous
//
#include <hip/hip_runtime.h>
#include <math.h>

// Problem constants (fixed by the reference)
#define NN   5000
#define BB   4
#define SEQ  128
#define OUTC 128
#define EE   80000
#define KTOT 384   // [X | Txo | Txi]
#define CTOT 256   // interleaved: col cc = 2*o + gate (gate 0=Z, 1=H)
#define MTOT (BB * NN)   // 20000
#define MPAD 20096       // 157 * 128
#define CAP  64          // bucket capacity; Binom(80000,1/5000) max ~40 << 64
#define EBLK 313         // ceil(EE/256)
#define FBLK 384         // CTOT*KTOT/256 weight-fold blocks
#define XBLK 1250        // x->bf16 convert blocks (320000 threads x 8 elems)

typedef __attribute__((ext_vector_type(8))) short bf16x8;
typedef __attribute__((ext_vector_type(4))) float f32x4;

__device__ inline unsigned short f2bf(float f) {   // RNE float->bf16
    union { float f; unsigned u; } a; a.f = f;
    unsigned r = a.u + 0x7FFF + ((a.u >> 16) & 1);
    return (unsigned short)(r >> 16);
}

// ---------------------------------------------------------------------------
// Zero deg/cnt region: 20000 floats.
// ---------------------------------------------------------------------------
__global__ __launch_bounds__(256) void k_zero(float* __restrict__ z) {
    int i = blockIdx.x * blockDim.x + threadIdx.x;
    if (i < 5000) {
        f32x4 zz = {0.f, 0.f, 0.f, 0.f};
        *(f32x4*)&z[i * 4] = zz;
    }
}

// ---------------------------------------------------------------------------
// One launch, three block roles (block-uniform branch):
//  [0,EBLK): edge pass — weighted degrees (atomic) + fixed-stride buckets.
//  [EBLK,EBLK+FBLK): weight fold WT[cc][k] bf16 (cc=2o+gate) + bias.
//  [EBLK+FBLK,..+XBLK): x -> bf16 copy (xb16), 8 elems/thread.
// ---------------------------------------------------------------------------
__global__ __launch_bounds__(256) void k_bucket_fold(
        const int* __restrict__ ei, const float* __restrict__ ew,
        const float* __restrict__ x,
        const float* __restrict__ Wz, const float* __restrict__ bz,
        const float* __restrict__ Wh, const float* __restrict__ bh,
        float* deg_out, float* deg_in,
        unsigned* cnt_in, unsigned* cnt_out,
        int2* __restrict__ bin, int2* __restrict__ bout,
        unsigned short* __restrict__ WT, float* __restrict__ bcat2,
        unsigned short* __restrict__ xb16) {
    int bid = blockIdx.x;
    if (bid < EBLK) {
        int e = bid * 256 + threadIdx.x;
        if (e >= EE) return;
        int s = ei[e], d = ei[EE + e];
        float w = ew[e];
        atomicAdd(&deg_out[s], w);
        atomicAdd(&deg_in[d], w);
        unsigned p = atomicAdd(&cnt_in[d], 1u);
        if (p < CAP) bin[((size_t)d << 6) + p] = make_int2(s, __float_as_int(w));
        unsigned q = atomicAdd(&cnt_out[s], 1u);
        if (q < CAP) bout[((size_t)s << 6) + q] = make_int2(d, __float_as_int(w));
    } else if (bid < EBLK + FBLK) {
        int i = (bid - EBLK) * 256 + threadIdx.x;   // [0, CTOT*KTOT)
        if (i < CTOT) bcat2[i] = (i & 1) ? bh[i >> 1] : bz[i >> 1];
        int cc = i / KTOT, k = i % KTOT;
        int gate = cc & 1, o = cc >> 1;
        const float* W = gate ? Wh : Wz;
        float v;
        if (k < 128)      v = W[(size_t)k * 128 + o] + W[(size_t)(512 + k) * 128 + o];
        else if (k < 256) v = W[(size_t)(256 + (k - 128)) * 128 + o];
        else              v = W[(size_t)(768 + (k - 256)) * 128 + o];
        WT[(size_t)cc * KTOT + k] = f2bf(v);
    } else {
        int j = (bid - EBLK - FBLK) * 256 + threadIdx.x;   // [0, 320000)
        if (j < (BB * NN * SEQ) / 8) {
            const float4* xp = (const float4*)x;
            float4 v0 = xp[(size_t)j * 2], v1 = xp[(size_t)j * 2 + 1];
            uint4 pk;
            pk.x = (unsigned)f2bf(v0.x) | ((unsigned)f2bf(v0.y) << 16);
            pk.y = (unsigned)f2bf(v0.z) | ((unsigned)f2bf(v0.w) << 16);
            pk.z = (unsigned)f2bf(v1.x) | ((unsigned)f2bf(v1.y) << 16);
            pk.w = (unsigned)f2bf(v1.z) | ((unsigned)f2bf(v1.w) << 16);
            ((uint4*)xb16)[j] = pk;
        }
    }
}

// ---------------------------------------------------------------------------
// Diffusion from bf16 x. One wave per (node,batch). Lane l: slot h=l>>4
// (row j+h), col group q=l&15 (8 cols). One uint4 load = 8 bf16 cols; a
// wave-load covers 4 rows x 128 cols (1 KB). Lists staged in wave-private
// LDS padded to multiple of 4 with cf=0 dummies. Cross-slot reduce via
// shfl_xor(16/32). Stores: h=0 Txo (Inb cols 0-127), h=1 Txi (128-255);
// X is NOT copied (k_mm reads xb16 directly).
// XCD-batch swizzle: blockIdx&7 -> each XCD's L2 holds one batch's x slice.
// ---------------------------------------------------------------------------
#define ACC8(A, v, cf) {                                              \
    A[0] += (cf) * __uint_as_float((v).x << 16);                      \
    A[1] += (cf) * __uint_as_float((v).x & 0xFFFF0000u);              \
    A[2] += (cf) * __uint_as_float((v).y << 16);                      \
    A[3] += (cf) * __uint_as_float((v).y & 0xFFFF0000u);              \
    A[4] += (cf) * __uint_as_float((v).z << 16);                      \
    A[5] += (cf) * __uint_as_float((v).z & 0xFFFF0000u);              \
    A[6] += (cf) * __uint_as_float((v).w << 16);                      \
    A[7] += (cf) * __uint_as_float((v).w & 0xFFFF0000u); }

__global__ __launch_bounds__(256) void k_diffuse(
        const unsigned short* __restrict__ xb16,
        const float* __restrict__ deg_out, const float* __restrict__ deg_in,
        const unsigned* __restrict__ cnt_in, const unsigned* __restrict__ cnt_out,
        const int2* __restrict__ bin, const int2* __restrict__ bout,
        unsigned short* __restrict__ Inb) {
    __shared__ int2 sbA[4][CAP + 4], sbB[4][CAP + 4];
    int bid = blockIdx.x;
    int slot = bid & 7, pos = bid >> 3;
    int b = slot >> 1;
    int wv = threadIdx.x >> 6;
    int n = (pos * 2 + (slot & 1)) * 4 + wv;
    int l = threadIdx.x & 63;
    int h = l >> 4, q = l & 15;
    const unsigned short* xb = xb16 + (size_t)b * NN * SEQ;

    int mi = (int)min(cnt_in[n], (unsigned)CAP);
    int mo = (int)min(cnt_out[n], (unsigned)CAP);
    if (l < mi) {   // coef_o = w * dinv_out[src]
        int2 e = bin[((size_t)n << 6) + l];
        float dg = deg_out[e.x];
        float cf = dg > 0.f ? __int_as_float(e.y) / dg : 0.f;
        sbA[wv][l] = make_int2(e.x, __float_as_int(cf));
    } else if (l < ((mi + 3) & ~3)) {
        sbA[wv][l] = make_int2(0, 0);   // pad to multiple of 4
    }
    if (l < mo) {   // coef_i = w * dinv_in[dst]
        int2 e = bout[((size_t)n << 6) + l];
        float dg = deg_in[e.x];
        float cf = dg > 0.f ? __int_as_float(e.y) / dg : 0.f;
        sbB[wv][l] = make_int2(e.x, __float_as_int(cf));
    } else if (l < ((mo + 3) & ~3)) {
        sbB[wv][l] = make_int2(0, 0);
    }
    int mie = (mi + 3) & ~3, moe = (mo + 3) & ~3;

    float ao[8] = {0.f, 0.f, 0.f, 0.f, 0.f, 0.f, 0.f, 0.f};
    float ai[8] = {0.f, 0.f, 0.f, 0.f, 0.f, 0.f, 0.f, 0.f};
    int j = 0;
    for (; j + 7 < mie; j += 8) {   // 2 loads in flight
        int2 e0 = sbA[wv][j + h], e1 = sbA[wv][j + 4 + h];
        uint4 v0 = *(const uint4*)&xb[(size_t)e0.x * SEQ + 8 * q];
        uint4 v1 = *(const uint4*)&xb[(size_t)e1.x * SEQ + 8 * q];
        float c0 = __int_as_float(e0.y), c1 = __int_as_float(e1.y);
        ACC8(ao, v0, c0);
        ACC8(ao, v1, c1);
    }
    for (; j < mie; j += 4) {
        int2 e0 = sbA[wv][j + h];
        uint4 v0 = *(const uint4*)&xb[(size_t)e0.x * SEQ + 8 * q];
        float c0 = __int_as_float(e0.y);
        ACC8(ao, v0, c0);
    }
    j = 0;
    for (; j + 7 < moe; j += 8) {
        int2 e0 = sbB[wv][j + h], e1 = sbB[wv][j + 4 + h];
        uint4 v0 = *(const uint4*)&xb[(size_t)e0.x * SEQ + 8 * q];
        uint4 v1 = *(const uint4*)&xb[(size_t)e1.x * SEQ + 8 * q];
        float c0 = __int_as_float(e0.y), c1 = __int_as_float(e1.y);
        ACC8(ai, v0, c0);
        ACC8(ai, v1, c1);
    }
    for (; j < moe; j += 4) {
        int2 e0 = sbB[wv][j + h];
        uint4 v0 = *(const uint4*)&xb[(size_t)e0.x * SEQ + 8 * q];
        float c0 = __int_as_float(e0.y);
        ACC8(ai, v0, c0);
    }

    // reduce over the 4 row-slots (lanes l, l^16, l^32, l^48)
#pragma unroll
    for (int r = 0; r < 8; ++r) {
        ao[r] += __shfl_xor(ao[r], 16); ao[r] += __shfl_xor(ao[r], 32);
        ai[r] += __shfl_xor(ai[r], 16); ai[r] += __shfl_xor(ai[r], 32);
    }

    unsigned short* rw = Inb + (size_t)(b * NN + n) * 256;
    if (h == 0) {          // Txo -> Inb cols 0..127
        uint4 pk;
        pk.x = (unsigned)f2bf(ao[0]) | ((unsigned)f2bf(ao[1]) << 16);
        pk.y = (unsigned)f2bf(ao[2]) | ((unsigned)f2bf(ao[3]) << 16);
        pk.z = (unsigned)f2bf(ao[4]) | ((unsigned)f2bf(ao[5]) << 16);
        pk.w = (unsigned)f2bf(ao[6]) | ((unsigned)f2bf(ao[7]) << 16);
        *(uint4*)&rw[8 * q] = pk;
    } else if (h == 1) {   // Txi -> Inb cols 128..255
        uint4 pk;
        pk.x = (unsigned)f2bf(ai[0]) | ((unsigned)f2bf(ai[1]) << 16);
        pk.y = (unsigned)f2bf(ai[2]) | ((unsigned)f2bf(ai[3]) << 16);
        pk.z = (unsigned)f2bf(ai[4]) | ((unsigned)f2bf(ai[5]) << 16);
        pk.w = (unsigned)f2bf(ai[6]) | ((unsigned)f2bf(ai[7]) << 16);
        *(uint4*)&rw[128 + 8 * q] = pk;
    }
}

// ---------------------------------------------------------------------------
// MFMA GEMM + fused epilogue. 8 waves/block (512 thr), wave-tile 64x32
// (wr=w>>2 row half, wc=w&3 col quarter) -> 2512 waves total (~2.5/SIMD vs
// 1.2 before: stalls now hidden by TLP). Each wave stages exactly 1 A-frag +
// 1 B-frag per K-step (f = w). A source: k<128 from xb16 directly (per-lane
// row ptr), k>=128 from Inb[r][256] (Txo|Txi). 3-buffer counted-vmcnt
// pipeline: steady-state vmcnt(2) waits only own stage(ks); barrier makes it
// all-waves. Epilogue: even lane 1/(1+e^z)=1-sigm, odd lane tanh; shfl_xor(1).
// ---------------------------------------------------------------------------
__global__ __launch_bounds__(512) void k_mm(
        const unsigned short* __restrict__ xb16,
        const unsigned short* __restrict__ Inb, const unsigned short* __restrict__ WT,
        const float* __restrict__ bcat2, float* __restrict__ out) {
    __shared__ unsigned short lA[3][4096];  // [buf][frag f*512 + lane*8]
    __shared__ unsigned short lB[3][4096];
    int t = threadIdx.x, w = t >> 6, l = t & 63;
    int lr = l & 15, lk = l >> 4;
    int n0 = blockIdx.x * 128;
    int c0 = blockIdx.y * 128;
    int wr = w >> 2, wc = w & 3;
    f32x4 acc[4][2] = {};

    // per-lane source rows for this wave's staged fragment (f == w)
    int r = n0 + w * 16 + lr;
    int bidx = (r >= 15000) ? 3 : (r >= 10000) ? 2 : (r >= 5000) ? 1 : 0;
    const unsigned short* xrow = xb16 + ((size_t)bidx * NN + (r - bidx * NN)) * SEQ;
    const unsigned short* irow = Inb + (size_t)r * 256;
    const unsigned short* wrow = WT + (size_t)(c0 + w * 16 + lr) * KTOT;

#define STAGE(buf, k0)                                                            \
    {                                                                             \
        const unsigned short* sa = ((k0) < 128) ? (xrow + (k0) + lk * 8)          \
                                                : (irow + ((k0) - 128) + lk * 8); \
        __builtin_amdgcn_global_load_lds(                                         \
            (const __attribute__((address_space(1))) void*)sa,                    \
            (__attribute__((address_space(3))) void*)&lA[buf][w * 512], 16, 0, 0);\
        const unsigned short* sb = wrow + (k0) + lk * 8;                          \
        __builtin_amdgcn_global_load_lds(                                         \
            (const __attribute__((address_space(1))) void*)sb,                    \
            (__attribute__((address_space(3))) void*)&lB[buf][w * 512], 16, 0, 0);\
    }

    STAGE(0, 0);
    STAGE(1, 32);

#pragma unroll
    for (int ks = 0; ks < 12; ++ks) {
        if (ks < 11) asm volatile("s_waitcnt vmcnt(2)" ::: "memory");
        else         asm volatile("s_waitcnt vmcnt(0)" ::: "memory");
        __builtin_amdgcn_s_barrier();
        const int bf = ks % 3;
        bf16x8 a[4], bfr[2];
#pragma unroll
        for (int i = 0; i < 4; ++i) a[i] = *(const bf16x8*)&lA[bf][(wr * 4 + i) * 512 + l * 8];
#pragma unroll
        for (int jj = 0; jj < 2; ++jj) bfr[jj] = *(const bf16x8*)&lB[bf][(wc * 2 + jj) * 512 + l * 8];
#pragma unroll
        for (int i = 0; i < 4; ++i)
#pragma unroll
            for (int jj = 0; jj < 2; ++jj)
                acc[i][jj] = __builtin_amdgcn_mfma_f32_16x16x32_bf16(a[i], bfr[jj], acc[i][jj], 0, 0, 0);
        if (ks + 2 < 12) STAGE((ks + 2) % 3, (ks + 2) * 32);
    }
#undef STAGE

    // Epilogue: row = n0+wr*64+i*16+lk*4+rr, col cc = c0+wc*32+jj*16+lr
    int row_base = n0 + wr * 64;
    bool odd = (l & 1);
#pragma unroll
    for (int jj = 0; jj < 2; ++jj) {
        int cc = c0 + wc * 32 + jj * 16 + lr;
        float bias = bcat2[cc];
        int o = cc >> 1;
#pragma unroll
        for (int i = 0; i < 4; ++i) {
#pragma unroll
            for (int rr = 0; rr < 4; ++rr) {
                float v = acc[i][jj][rr] + bias;
                // even lane (v=z_pre): u = 1/(1+e^v)    = 1 - sigmoid(v)
                // odd  lane (v=h_pre): u = 1-2/(e^2v+1) = tanh(v)
                float ex = __expf(odd ? 2.f * v : v);
                float u = odd ? (1.f - 2.f / (ex + 1.f)) : (1.f / (1.f + ex));
                float g = __shfl_xor(u, 1);
                if (!odd) {
                    int row = row_base + i * 16 + lk * 4 + rr;
                    if (row < MTOT) out[(size_t)row * OUTC + o] = u * g;
                }
            }
        }
    }
}

// ---------------------------------------------------------------------------
extern "C" void kernel_launch(void* const* d_in, const int* in_sizes, int n_in,
                              void* d_out, int out_size, void* d_ws, size_t ws_size,
                              hipStream_t stream) {
    const float* x  = (const float*)d_in[0];
    const int*   ei = (const int*)d_in[1];
    const float* ew = (const float*)d_in[2];
    const float* Wz = (const float*)d_in[3];
    const float* bz = (const float*)d_in[4];
    // d_in[5]=Wr, d_in[6]=br dead (H0==0 -> Xc2==Xc, R unused)
    const float* Wh = (const float*)d_in[7];
    const float* bh = (const float*)d_in[8];

    float* ws = (float*)d_ws;
    float*    deg_out = ws + 0;                        // 5000
    float*    deg_in  = ws + 5000;                     // 5000
    unsigned* cnt_in  = (unsigned*)(ws + 10000);       // 5000
    unsigned* cnt_out = (unsigned*)(ws + 15000);       // 5000
    float*    bcat2   = ws + 20000;                    // 256
    unsigned short* WT = (unsigned short*)(ws + 20256);  // 256*384 bf16 (49152 fl)
    int2*     bin  = (int2*)(ws + 69408);              // 5000*64 int2 (640000 fl)
    int2*     bout = (int2*)(ws + 709408);             // 5000*64 int2 (640000 fl)
    unsigned short* xb16 = (unsigned short*)(ws + 1349408); // 2.56M bf16 (1.28M fl)
    unsigned short* Inb = (unsigned short*)(ws + 2629408);  // MPAD*256 bf16

    k_zero<<<20, 256, 0, stream>>>(ws);
    k_bucket_fold<<<EBLK + FBLK + XBLK, 256, 0, stream>>>(
        ei, ew, x, Wz, bz, Wh, bh, deg_out, deg_in, cnt_in, cnt_out,
        bin, bout, WT, bcat2, xb16);
    k_diffuse<<<NN, 256, 0, stream>>>(xb16, deg_out, deg_in, cnt_in, cnt_out,
                                      bin, bout, Inb);
    dim3 g(MPAD / 128, 2);
    k_mm<<<g, 512, 0, stream>>>(xb16, Inb, WT, bcat2, (float*)d_out);
}